// Round 2
// baseline (1514.010 us; speedup 1.0000x reference)
//
#include <hip/hip_runtime.h>

#define HD 192
#define FD0 128
#define NG 256
#define BNEPS 1e-5f

#define AGG_S   2097152.0f        // 2^21 fixed-point scale for aggregation
#define AGG_IS  (1.0f / 2097152.0f)
#define STAT_S  1048576.0f        // 2^20 fixed-point scale for BN stats
#define STAT_IS (1.0f / 1048576.0f)

static inline int idiv(int a, int b) { return (a + b - 1) / b; }

// ---------------- edge scatter-add (fixed-point, deterministic) ----------------
template<int FD>
__global__ __launch_bounds__(256) void scatter_kernel(
    const float* __restrict__ x, const int* __restrict__ src,
    const int* __restrict__ dst, int* __restrict__ aggq, int E)
{
    const int e = blockIdx.x * 4 + (threadIdx.x >> 6);
    if (e >= E) return;
    const int l = threadIdx.x & 63;
    const int s = src[e], d = dst[e];
    const float* xs = x + (size_t)s * FD;
    int* ad = aggq + (size_t)d * FD;
#pragma unroll
    for (int f = 0; f < FD; f += 64) {
        const int q = __float2int_rn(xs[f + l] * AGG_S);
        atomicAdd(&ad[f + l], q);
    }
}

// -------- H = A@Wr^T + bias + X@Wt^T ; accumulate column sum/sumsq (fixed-pt) ----
// block: 256 threads, tile 64 rows x 192 cols; thread = 4 rows x 12 cols
template<int K>
__global__ __launch_bounds__(256) void gemm_kernel(
    const int* __restrict__ Aq, const float* X,
    const float* __restrict__ Wr, const float* __restrict__ Wt,
    const float* __restrict__ bias,
    float* Hout, long long* __restrict__ statsq, int N)
{
    __shared__ float As[32][64];
    __shared__ float Ws[32][HD];
    const int tid = threadIdx.x;
    const int tc = tid & 15;   // 16 col groups * 12 cols
    const int tr = tid >> 4;   // 16 row groups * 4 rows
    const int row0 = blockIdx.x * 64;

    float acc[4][12];
#pragma unroll
    for (int r = 0; r < 4; ++r)
#pragma unroll
        for (int c = 0; c < 12; ++c) acc[r][c] = 0.f;

#pragma unroll
    for (int phase = 0; phase < 2; ++phase) {
        const float* W = phase ? Wt : Wr;
        for (int k0 = 0; k0 < K; k0 += 32) {
            __syncthreads();
            {   // stage 64x32 tile of M (transposed into As[k][row])
                const int r = tid & 63;
                const int kb = (tid >> 6) << 3;
                const int grow = row0 + r;
                const int rowc = grow < N ? grow : (N - 1);
                float v[8];
                if (phase == 0) {
                    const int* g = Aq + (size_t)rowc * K + (k0 + kb);
                    const int4 q0 = *(const int4*)g;
                    const int4 q1 = *(const int4*)(g + 4);
                    v[0] = (float)q0.x * AGG_IS; v[1] = (float)q0.y * AGG_IS;
                    v[2] = (float)q0.z * AGG_IS; v[3] = (float)q0.w * AGG_IS;
                    v[4] = (float)q1.x * AGG_IS; v[5] = (float)q1.y * AGG_IS;
                    v[6] = (float)q1.z * AGG_IS; v[7] = (float)q1.w * AGG_IS;
                } else {
                    const float* g = X + (size_t)rowc * K + (k0 + kb);
                    const float4 f0 = *(const float4*)g;
                    const float4 f1 = *(const float4*)(g + 4);
                    v[0] = f0.x; v[1] = f0.y; v[2] = f0.z; v[3] = f0.w;
                    v[4] = f1.x; v[5] = f1.y; v[6] = f1.z; v[7] = f1.w;
                }
                if (grow >= N)
#pragma unroll
                    for (int i = 0; i < 8; ++i) v[i] = 0.f;
#pragma unroll
                for (int i = 0; i < 8; ++i) As[kb + i][r] = v[i];
            }
            if (tid < HD) {  // stage 192x32 tile of W (transposed into Ws[k][j])
                const float* g = W + (size_t)tid * K + k0;
#pragma unroll
                for (int kk = 0; kk < 32; kk += 4) {
                    float4 v = *(const float4*)(g + kk);
                    Ws[kk + 0][tid] = v.x; Ws[kk + 1][tid] = v.y;
                    Ws[kk + 2][tid] = v.z; Ws[kk + 3][tid] = v.w;
                }
            }
            __syncthreads();
#pragma unroll
            for (int k = 0; k < 32; ++k) {
                const float4 av = *(const float4*)&As[k][tr << 2];
                const float a0 = av.x, a1 = av.y, a2 = av.z, a3 = av.w;
                const float4 w0 = *(const float4*)&Ws[k][tc * 12];
                const float4 w1 = *(const float4*)&Ws[k][tc * 12 + 4];
                const float4 w2 = *(const float4*)&Ws[k][tc * 12 + 8];
                const float wv[12] = {w0.x, w0.y, w0.z, w0.w,
                                      w1.x, w1.y, w1.z, w1.w,
                                      w2.x, w2.y, w2.z, w2.w};
#pragma unroll
                for (int c = 0; c < 12; ++c) {
                    acc[0][c] = fmaf(a0, wv[c], acc[0][c]);
                    acc[1][c] = fmaf(a1, wv[c], acc[1][c]);
                    acc[2][c] = fmaf(a2, wv[c], acc[2][c]);
                    acc[3][c] = fmaf(a3, wv[c], acc[3][c]);
                }
            }
        }
    }

    float bv[12];
#pragma unroll
    for (int c = 0; c < 12; ++c) bv[c] = bias[tc * 12 + c];

    float s1[12], s2[12];
#pragma unroll
    for (int c = 0; c < 12; ++c) { s1[c] = 0.f; s2[c] = 0.f; }

#pragma unroll
    for (int r = 0; r < 4; ++r) {
        const int grow = row0 + (tr << 2) + r;
        if (grow < N) {
            float v[12];
#pragma unroll
            for (int c = 0; c < 12; ++c) {
                v[c] = acc[r][c] + bv[c];
                s1[c] += v[c];
                s2[c] += v[c] * v[c];
            }
            float* o = Hout + (size_t)grow * HD + tc * 12;
            *(float4*)(o)     = make_float4(v[0], v[1], v[2], v[3]);
            *(float4*)(o + 4) = make_float4(v[4], v[5], v[6], v[7]);
            *(float4*)(o + 8) = make_float4(v[8], v[9], v[10], v[11]);
        }
    }

    // block-level reduction of BN partial sums (reuse Ws as scratch),
    // then ONE fixed-point atomic per column per block -> deterministic.
    __syncthreads();
#pragma unroll
    for (int c = 0; c < 12; ++c) {
        Ws[tr][tc * 12 + c]      = s1[c];
        Ws[16 + tr][tc * 12 + c] = s2[c];
    }
    __syncthreads();
    if (tid < HD) {
        float a1 = 0.f, a2 = 0.f;
#pragma unroll
        for (int r = 0; r < 16; ++r) { a1 += Ws[r][tid]; a2 += Ws[16 + r][tid]; }
        atomicAdd((unsigned long long*)&statsq[tid],
                  (unsigned long long)(long long)llrintf(a1 * STAT_S));
        atomicAdd((unsigned long long*)&statsq[HD + tid],
                  (unsigned long long)(long long)llrintf(a2 * STAT_S));
    }
}

// ---------------- BN: scale/shift from fixed-point sum/sumsq ----------------
__global__ void stats_finalize(const long long* __restrict__ statsq,
    const float* __restrict__ gamma, const float* __restrict__ beta,
    float* __restrict__ scsh, int N)
{
    const int c = threadIdx.x;
    if (c >= HD) return;
    const float inv = 1.0f / (float)N;
    const float sum   = (float)statsq[c] * STAT_IS;
    const float sumsq = (float)statsq[HD + c] * STAT_IS;
    const float mu  = sum * inv;
    const float var = sumsq * inv - mu * mu;
    const float sc  = gamma[c] * rsqrtf(var + BNEPS);
    scsh[c]      = sc;
    scsh[HD + c] = beta[c] - mu * sc;
}

// ---------------- h = relu(h*scale + shift), in place ----------------
__global__ __launch_bounds__(256) void norm_relu(float* h,
    const float* __restrict__ scsh, int N)
{
    const int idx = blockIdx.x * 256 + threadIdx.x;  // float4 granule
    const int total = N * (HD / 4);
    if (idx >= total) return;
    const int c4 = idx % (HD / 4);
    float4 v = ((float4*)h)[idx];
    const float4 sc = ((const float4*)scsh)[c4];
    const float4 sh = ((const float4*)(scsh + HD))[c4];
    v.x = fmaxf(0.f, fmaf(v.x, sc.x, sh.x));
    v.y = fmaxf(0.f, fmaf(v.y, sc.y, sh.y));
    v.z = fmaxf(0.f, fmaf(v.z, sc.z, sh.z));
    v.w = fmaxf(0.f, fmaf(v.w, sc.w, sh.w));
    ((float4*)h)[idx] = v;
}

// ------- fused mean-pool (deterministic segment sum) + MLP head, 1 block/graph ----
__global__ __launch_bounds__(192) void pool_head_kernel(
    const float* __restrict__ h, const int* __restrict__ batch, int N,
    const float* __restrict__ w1, const float* __restrict__ b1,
    const float* __restrict__ w2, const float* __restrict__ b2,
    const float* __restrict__ ow, const float* __restrict__ ob,
    float* __restrict__ out)
{
    __shared__ float gv[HD];
    __shared__ float h1[HD];
    __shared__ float h2[HD];
    const int g = blockIdx.x;
    const int t = threadIdx.x;

    // lower_bound(batch, g) and lower_bound(batch, g+1) on sorted batch
    int lo = 0, hi = N;
    while (lo < hi) { int m = (lo + hi) >> 1; if (batch[m] < g) lo = m + 1; else hi = m; }
    const int start = lo;
    hi = N;
    while (lo < hi) { int m = (lo + hi) >> 1; if (batch[m] < g + 1) lo = m + 1; else hi = m; }
    const int end = lo;

    float s = 0.f;
    for (int r = start; r < end; ++r) s += h[(size_t)r * HD + t];
    const float cnt = fmaxf((float)(end - start), 1.0f);
    gv[t] = s / cnt;
    __syncthreads();
    {
        float acc = b1[t];
        const float* wr = w1 + (size_t)t * HD;
#pragma unroll 4
        for (int k = 0; k < HD; ++k) acc = fmaf(gv[k], wr[k], acc);
        h1[t] = fmaxf(acc, 0.f);
    }
    __syncthreads();
    {
        float acc = b2[t];
        const float* wr = w2 + (size_t)t * HD;
#pragma unroll 4
        for (int k = 0; k < HD; ++k) acc = fmaf(h1[k], wr[k], acc);
        h2[t] = acc * ow[t];
    }
    __syncthreads();
    if (t == 0) {
        float acc = ob[0];
        for (int k = 0; k < HD; ++k) acc += h2[k];
        out[g] = acc;
    }
}

extern "C" void kernel_launch(void* const* d_in, const int* in_sizes, int n_in,
                              void* d_out, int out_size, void* d_ws, size_t ws_size,
                              hipStream_t stream)
{
    const float* x       = (const float*)d_in[0];
    const int*   ei      = (const int*)d_in[1];
    const int*   batch   = (const int*)d_in[2];
    const float* w_rel0  = (const float*)d_in[4];
    const float* b_rel0  = (const float*)d_in[5];
    const float* w_root0 = (const float*)d_in[6];
    const float* w_rel   = (const float*)d_in[7];
    const float* b_rel   = (const float*)d_in[8];
    const float* w_root  = (const float*)d_in[9];
    const float* bn_g    = (const float*)d_in[10];
    const float* bn_b    = (const float*)d_in[11];
    const float* hw1     = (const float*)d_in[12];
    const float* hb1     = (const float*)d_in[13];
    const float* hw2     = (const float*)d_in[14];
    const float* hb2     = (const float*)d_in[15];
    const float* ow      = (const float*)d_in[16];
    const float* ob      = (const float*)d_in[17];
    float* out = (float*)d_out;

    const int N = in_sizes[0] / FD0;
    const int E = in_sizes[1] / 2;
    const int* src = ei;
    const int* dst = ei + E;

    char* ws = (char*)d_ws;
    const size_t featBytes = (size_t)N * HD * sizeof(float);
    int*       aggq   = (int*)ws;                          // N*HD int32
    float*     h      = (float*)(ws + featBytes);          // N*HD float
    long long* statsq = (long long*)(ws + 2 * featBytes);  // 2*HD int64
    float*     scsh   = (float*)(statsq + 2 * HD);         // 2*HD float

    const dim3 b256(256), b192(192);

    // ---- layer 0 (F=128 -> H=192)
    hipMemsetAsync(aggq, 0, (size_t)N * FD0 * sizeof(int), stream);
    hipMemsetAsync(statsq, 0, 2 * HD * sizeof(long long), stream);
    scatter_kernel<FD0><<<idiv(E, 4), b256, 0, stream>>>(x, src, dst, aggq, E);
    gemm_kernel<FD0><<<idiv(N, 64), b256, 0, stream>>>(aggq, x, w_rel0, w_root0,
                                                       b_rel0, h, statsq, N);
    stats_finalize<<<1, b192, 0, stream>>>(statsq, bn_g, bn_b, scsh, N);
    norm_relu<<<idiv(N * (HD / 4), 256), b256, 0, stream>>>(h, scsh, N);

    // ---- layers 1..3 (H -> H)
    for (int i = 0; i < 3; ++i) {
        hipMemsetAsync(aggq, 0, (size_t)N * HD * sizeof(int), stream);
        hipMemsetAsync(statsq, 0, 2 * HD * sizeof(long long), stream);
        scatter_kernel<HD><<<idiv(E, 4), b256, 0, stream>>>(h, src, dst, aggq, E);
        gemm_kernel<HD><<<idiv(N, 64), b256, 0, stream>>>(
            aggq, h, w_rel + (size_t)i * HD * HD, w_root + (size_t)i * HD * HD,
            b_rel + (size_t)i * HD, h, statsq, N);
        stats_finalize<<<1, b192, 0, stream>>>(statsq, bn_g + (size_t)(i + 1) * HD,
                                               bn_b + (size_t)(i + 1) * HD, scsh, N);
        norm_relu<<<idiv(N * (HD / 4), 256), b256, 0, stream>>>(h, scsh, N);
    }

    // ---- fused global mean pool + head
    pool_head_kernel<<<NG, b192, 0, stream>>>(h, batch, N, hw1, hb1, hw2, hb2,
                                              ow, ob, out);
}

// Round 4
// 960.223 us; speedup vs baseline: 1.5767x; 1.5767x over previous
//
#include <hip/hip_runtime.h>

#define HD 192
#define FD0 128
#define NG 256
#define BNEPS 1e-5f

#define AGG_S   2097152.0f        // 2^21 fixed-point scale for aggregation
#define AGG_IS  (1.0f / 2097152.0f)
#define STAT_S  1048576.0f        // 2^20 fixed-point scale for BN stats
#define STAT_IS (1.0f / 1048576.0f)

static inline int idiv(int a, int b) { return (a + b - 1) / b; }

// ---------------- CSR build: histogram of dst ----------------
__global__ __launch_bounds__(256) void hist_kernel(const int* __restrict__ dst,
                                                   int* __restrict__ deg, int E)
{
    const int e = blockIdx.x * 256 + threadIdx.x;
    if (e < E) atomicAdd(&deg[dst[e]], 1);
}

// ---------------- CSR build: exclusive scan (single block) ----------------
__global__ __launch_bounds__(1024) void scan_kernel(const int* __restrict__ deg,
                                                    int* __restrict__ rowptr, int N)
{
    __shared__ int sums[1024];
    const int t = threadIdx.x;
    const int C = (N + 1023) >> 10;
    const int lo = t * C;
    const int hi = (lo + C < N) ? (lo + C) : N;
    int s = 0;
    for (int i = lo; i < hi; ++i) s += deg[i];
    sums[t] = s;
    __syncthreads();
    for (int off = 1; off < 1024; off <<= 1) {
        int u = (t >= off) ? sums[t - off] : 0;
        __syncthreads();
        sums[t] += u;
        __syncthreads();
    }
    int run = (t == 0) ? 0 : sums[t - 1];
    for (int i = lo; i < hi; ++i) { rowptr[i] = run; run += deg[i]; }
    if (t == 1023) rowptr[N] = run;
}

// ---------------- CSR build: fill buckets with src ids ----------------
__global__ __launch_bounds__(256) void fill_kernel(const int* __restrict__ src,
    const int* __restrict__ dst, const int* __restrict__ rowptr,
    int* __restrict__ cursor, int* __restrict__ eidx, int E)
{
    const int e = blockIdx.x * 256 + threadIdx.x;
    if (e >= E) return;
    const int d = dst[e];
    const int p = atomicAdd(&cursor[d], 1);
    eidx[rowptr[d] + p] = src[e];
}

// ------- CSR gather-aggregate: aggq[n] = sum_{s in adj(n)} q(h[s]) -------
// one node per block-iteration; FD threads, thread = one feature column.
// integer accumulation -> order-independent -> deterministic.
template<int FD>
__global__ __launch_bounds__(192) void gather_kernel(
    const float* __restrict__ h, const int* __restrict__ rowptr,
    const int* __restrict__ eidx, int* __restrict__ aggq, int N)
{
    const int t = threadIdx.x;
    for (int n = blockIdx.x; n < N; n += gridDim.x) {
        const int beg = rowptr[n], end = rowptr[n + 1];
        int acc = 0;
        int j = beg;
        for (; j + 1 < end; j += 2) {
            const int s0 = eidx[j], s1 = eidx[j + 1];
            const float v0 = h[(size_t)s0 * FD + t];
            const float v1 = h[(size_t)s1 * FD + t];
            acc += __float2int_rn(v0 * AGG_S) + __float2int_rn(v1 * AGG_S);
        }
        if (j < end)
            acc += __float2int_rn(h[(size_t)eidx[j] * FD + t] * AGG_S);
        aggq[(size_t)n * FD + t] = acc;
    }
}

// -------- H = A@Wr^T + bias + X@Wt^T ; accumulate column sum/sumsq (fixed-pt) ----
// block: 256 threads, tile 64 rows x 192 cols; thread = 4 rows x 12 cols
template<int K>
__global__ __launch_bounds__(256) void gemm_kernel(
    const int* __restrict__ Aq, const float* X,
    const float* __restrict__ Wr, const float* __restrict__ Wt,
    const float* __restrict__ bias,
    float* Hout, long long* __restrict__ statsq, int N)
{
    __shared__ float As[32][64];
    __shared__ float Ws[32][HD];
    const int tid = threadIdx.x;
    const int tc = tid & 15;   // 16 col groups * 12 cols
    const int tr = tid >> 4;   // 16 row groups * 4 rows
    const int row0 = blockIdx.x * 64;

    float acc[4][12];
#pragma unroll
    for (int r = 0; r < 4; ++r)
#pragma unroll
        for (int c = 0; c < 12; ++c) acc[r][c] = 0.f;

#pragma unroll
    for (int phase = 0; phase < 2; ++phase) {
        const float* W = phase ? Wt : Wr;
        for (int k0 = 0; k0 < K; k0 += 32) {
            __syncthreads();
            {   // stage 64x32 tile of M (transposed into As[k][row])
                const int r = tid & 63;
                const int kb = (tid >> 6) << 3;
                const int grow = row0 + r;
                const int rowc = grow < N ? grow : (N - 1);
                float v[8];
                if (phase == 0) {
                    const int* g = Aq + (size_t)rowc * K + (k0 + kb);
                    const int4 q0 = *(const int4*)g;
                    const int4 q1 = *(const int4*)(g + 4);
                    v[0] = (float)q0.x * AGG_IS; v[1] = (float)q0.y * AGG_IS;
                    v[2] = (float)q0.z * AGG_IS; v[3] = (float)q0.w * AGG_IS;
                    v[4] = (float)q1.x * AGG_IS; v[5] = (float)q1.y * AGG_IS;
                    v[6] = (float)q1.z * AGG_IS; v[7] = (float)q1.w * AGG_IS;
                } else {
                    const float* g = X + (size_t)rowc * K + (k0 + kb);
                    const float4 f0 = *(const float4*)g;
                    const float4 f1 = *(const float4*)(g + 4);
                    v[0] = f0.x; v[1] = f0.y; v[2] = f0.z; v[3] = f0.w;
                    v[4] = f1.x; v[5] = f1.y; v[6] = f1.z; v[7] = f1.w;
                }
                if (grow >= N)
#pragma unroll
                    for (int i = 0; i < 8; ++i) v[i] = 0.f;
#pragma unroll
                for (int i = 0; i < 8; ++i) As[kb + i][r] = v[i];
            }
            if (tid < HD) {  // stage 192x32 tile of W (transposed into Ws[k][j])
                const float* g = W + (size_t)tid * K + k0;
#pragma unroll
                for (int kk = 0; kk < 32; kk += 4) {
                    float4 v = *(const float4*)(g + kk);
                    Ws[kk + 0][tid] = v.x; Ws[kk + 1][tid] = v.y;
                    Ws[kk + 2][tid] = v.z; Ws[kk + 3][tid] = v.w;
                }
            }
            __syncthreads();
#pragma unroll
            for (int k = 0; k < 32; ++k) {
                const float4 av = *(const float4*)&As[k][tr << 2];
                const float a0 = av.x, a1 = av.y, a2 = av.z, a3 = av.w;
                const float4 w0 = *(const float4*)&Ws[k][tc * 12];
                const float4 w1 = *(const float4*)&Ws[k][tc * 12 + 4];
                const float4 w2 = *(const float4*)&Ws[k][tc * 12 + 8];
                const float wv[12] = {w0.x, w0.y, w0.z, w0.w,
                                      w1.x, w1.y, w1.z, w1.w,
                                      w2.x, w2.y, w2.z, w2.w};
#pragma unroll
                for (int c = 0; c < 12; ++c) {
                    acc[0][c] = fmaf(a0, wv[c], acc[0][c]);
                    acc[1][c] = fmaf(a1, wv[c], acc[1][c]);
                    acc[2][c] = fmaf(a2, wv[c], acc[2][c]);
                    acc[3][c] = fmaf(a3, wv[c], acc[3][c]);
                }
            }
        }
    }

    float bv[12];
#pragma unroll
    for (int c = 0; c < 12; ++c) bv[c] = bias[tc * 12 + c];

    float s1[12], s2[12];
#pragma unroll
    for (int c = 0; c < 12; ++c) { s1[c] = 0.f; s2[c] = 0.f; }

#pragma unroll
    for (int r = 0; r < 4; ++r) {
        const int grow = row0 + (tr << 2) + r;
        if (grow < N) {
            float v[12];
#pragma unroll
            for (int c = 0; c < 12; ++c) {
                v[c] = acc[r][c] + bv[c];
                s1[c] += v[c];
                s2[c] += v[c] * v[c];
            }
            float* o = Hout + (size_t)grow * HD + tc * 12;
            *(float4*)(o)     = make_float4(v[0], v[1], v[2], v[3]);
            *(float4*)(o + 4) = make_float4(v[4], v[5], v[6], v[7]);
            *(float4*)(o + 8) = make_float4(v[8], v[9], v[10], v[11]);
        }
    }

    // block-level reduction of BN partial sums, one fixed-point atomic per column.
    __syncthreads();
#pragma unroll
    for (int c = 0; c < 12; ++c) {
        Ws[tr][tc * 12 + c]      = s1[c];
        Ws[16 + tr][tc * 12 + c] = s2[c];
    }
    __syncthreads();
    if (tid < HD) {
        float a1 = 0.f, a2 = 0.f;
#pragma unroll
        for (int r = 0; r < 16; ++r) { a1 += Ws[r][tid]; a2 += Ws[16 + r][tid]; }
        atomicAdd((unsigned long long*)&statsq[tid],
                  (unsigned long long)(long long)llrintf(a1 * STAT_S));
        atomicAdd((unsigned long long*)&statsq[HD + tid],
                  (unsigned long long)(long long)llrintf(a2 * STAT_S));
    }
}

// ---------------- BN: scale/shift from fixed-point sum/sumsq ----------------
__global__ void stats_finalize(const long long* __restrict__ statsq,
    const float* __restrict__ gamma, const float* __restrict__ beta,
    float* __restrict__ scsh, int N)
{
    const int c = threadIdx.x;
    if (c >= HD) return;
    const float inv = 1.0f / (float)N;
    const float sum   = (float)statsq[c] * STAT_IS;
    const float sumsq = (float)statsq[HD + c] * STAT_IS;
    const float mu  = sum * inv;
    const float var = sumsq * inv - mu * mu;
    const float sc  = gamma[c] * rsqrtf(var + BNEPS);
    scsh[c]      = sc;
    scsh[HD + c] = beta[c] - mu * sc;
}

// ---------------- h = relu(h*scale + shift), in place ----------------
__global__ __launch_bounds__(256) void norm_relu(float* h,
    const float* __restrict__ scsh, int N)
{
    const int idx = blockIdx.x * 256 + threadIdx.x;  // float4 granule
    const int total = N * (HD / 4);
    if (idx >= total) return;
    const int c4 = idx % (HD / 4);
    float4 v = ((float4*)h)[idx];
    const float4 sc = ((const float4*)scsh)[c4];
    const float4 sh = ((const float4*)(scsh + HD))[c4];
    v.x = fmaxf(0.f, fmaf(v.x, sc.x, sh.x));
    v.y = fmaxf(0.f, fmaf(v.y, sc.y, sh.y));
    v.z = fmaxf(0.f, fmaf(v.z, sc.z, sh.z));
    v.w = fmaxf(0.f, fmaf(v.w, sc.w, sh.w));
    ((float4*)h)[idx] = v;
}

// ------- fused mean-pool (deterministic segment sum) + MLP head, 1 block/graph ----
__global__ __launch_bounds__(192) void pool_head_kernel(
    const float* __restrict__ h, const int* __restrict__ batch, int N,
    const float* __restrict__ w1, const float* __restrict__ b1,
    const float* __restrict__ w2, const float* __restrict__ b2,
    const float* __restrict__ ow, const float* __restrict__ ob,
    float* __restrict__ out)
{
    __shared__ float gv[HD];
    __shared__ float h1[HD];
    __shared__ float h2[HD];
    const int g = blockIdx.x;
    const int t = threadIdx.x;

    int lo = 0, hi = N;
    while (lo < hi) { int m = (lo + hi) >> 1; if (batch[m] < g) lo = m + 1; else hi = m; }
    const int start = lo;
    hi = N;
    while (lo < hi) { int m = (lo + hi) >> 1; if (batch[m] < g + 1) lo = m + 1; else hi = m; }
    const int end = lo;

    float s = 0.f;
    for (int r = start; r < end; ++r) s += h[(size_t)r * HD + t];
    const float cnt = fmaxf((float)(end - start), 1.0f);
    gv[t] = s / cnt;
    __syncthreads();
    {
        float acc = b1[t];
        const float* wr = w1 + (size_t)t * HD;
#pragma unroll 4
        for (int k = 0; k < HD; ++k) acc = fmaf(gv[k], wr[k], acc);
        h1[t] = fmaxf(acc, 0.f);
    }
    __syncthreads();
    {
        float acc = b2[t];
        const float* wr = w2 + (size_t)t * HD;
#pragma unroll 4
        for (int k = 0; k < HD; ++k) acc = fmaf(h1[k], wr[k], acc);
        h2[t] = acc * ow[t];
    }
    __syncthreads();
    if (t == 0) {
        float acc = ob[0];
        for (int k = 0; k < HD; ++k) acc += h2[k];
        out[g] = acc;
    }
}

extern "C" void kernel_launch(void* const* d_in, const int* in_sizes, int n_in,
                              void* d_out, int out_size, void* d_ws, size_t ws_size,
                              hipStream_t stream)
{
    const float* x       = (const float*)d_in[0];
    const int*   ei      = (const int*)d_in[1];
    const int*   batch   = (const int*)d_in[2];
    const float* w_rel0  = (const float*)d_in[4];
    const float* b_rel0  = (const float*)d_in[5];
    const float* w_root0 = (const float*)d_in[6];
    const float* w_rel   = (const float*)d_in[7];
    const float* b_rel   = (const float*)d_in[8];
    const float* w_root  = (const float*)d_in[9];
    const float* bn_g    = (const float*)d_in[10];
    const float* bn_b    = (const float*)d_in[11];
    const float* hw1     = (const float*)d_in[12];
    const float* hb1     = (const float*)d_in[13];
    const float* hw2     = (const float*)d_in[14];
    const float* hb2     = (const float*)d_in[15];
    const float* ow      = (const float*)d_in[16];
    const float* ob      = (const float*)d_in[17];
    float* out = (float*)d_out;

    const int N = in_sizes[0] / FD0;
    const int E = in_sizes[1] / 2;
    const int* src = ei;
    const int* dst = ei + E;

    char* ws = (char*)d_ws;
    const size_t featBytes = (size_t)N * HD * sizeof(float);
    int*       aggq   = (int*)ws;                          // N*HD int32
    float*     h      = (float*)(ws + featBytes);          // N*HD float
    long long* statsq = (long long*)(ws + 2 * featBytes);  // 2*HD int64
    float*     scsh   = (float*)(statsq + 2 * HD);         // 2*HD float
    int*       rowptr = (int*)(scsh + 2 * HD);             // N+1 int
    int*       deg    = rowptr + (N + 1);                  // N int (reused as cursor)
    int*       eidx   = deg + N;                           // E int

    const dim3 b256(256), b192(192);

    // ---- build CSR once (deterministic: int atomics + order-indep consumers)
    hipMemsetAsync(deg, 0, (size_t)N * sizeof(int), stream);
    hist_kernel<<<idiv(E, 256), b256, 0, stream>>>(dst, deg, E);
    scan_kernel<<<1, 1024, 0, stream>>>(deg, rowptr, N);
    hipMemsetAsync(deg, 0, (size_t)N * sizeof(int), stream);  // deg -> cursor
    fill_kernel<<<idiv(E, 256), b256, 0, stream>>>(src, dst, rowptr, deg, eidx, E);

    // ---- layer 0 (F=128 -> H=192)
    hipMemsetAsync(statsq, 0, 2 * HD * sizeof(long long), stream);
    gather_kernel<FD0><<<N, dim3(FD0), 0, stream>>>(x, rowptr, eidx, aggq, N);
    gemm_kernel<FD0><<<idiv(N, 64), b256, 0, stream>>>(aggq, x, w_rel0, w_root0,
                                                       b_rel0, h, statsq, N);
    stats_finalize<<<1, b192, 0, stream>>>(statsq, bn_g, bn_b, scsh, N);
    norm_relu<<<idiv(N * (HD / 4), 256), b256, 0, stream>>>(h, scsh, N);

    // ---- layers 1..3 (H -> H)
    for (int i = 0; i < 3; ++i) {
        hipMemsetAsync(statsq, 0, 2 * HD * sizeof(long long), stream);
        gather_kernel<HD><<<N, b192, 0, stream>>>(h, rowptr, eidx, aggq, N);
        gemm_kernel<HD><<<idiv(N, 64), b256, 0, stream>>>(
            aggq, h, w_rel + (size_t)i * HD * HD, w_root + (size_t)i * HD * HD,
            b_rel + (size_t)i * HD, h, statsq, N);
        stats_finalize<<<1, b192, 0, stream>>>(statsq, bn_g + (size_t)(i + 1) * HD,
                                               bn_b + (size_t)(i + 1) * HD, scsh, N);
        norm_relu<<<idiv(N * (HD / 4), 256), b256, 0, stream>>>(h, scsh, N);
    }

    // ---- fused global mean pool + head
    pool_head_kernel<<<NG, b192, 0, stream>>>(h, batch, N, hw1, hb1, hw2, hb2,
                                              ow, ob, out);
}

// Round 5
// 815.292 us; speedup vs baseline: 1.8570x; 1.1778x over previous
//
#include <hip/hip_runtime.h>

#define HD 192
#define FD0 128
#define NG 256
#define BNEPS 1e-5f

#define AGG_S   2097152.0f        // 2^21 fixed-point scale for aggregation
#define AGG_IS  (1.0f / 2097152.0f)
#define STAT_S  1048576.0f        // 2^20 fixed-point scale for BN stats
#define STAT_IS (1.0f / 1048576.0f)

typedef unsigned short u16;
typedef __attribute__((ext_vector_type(8))) short bf16x8;
typedef __attribute__((ext_vector_type(4))) float f32x4;

static inline int idiv(int a, int b) { return (a + b - 1) / b; }

__device__ __forceinline__ float b2f(u16 u) {
    unsigned int v = ((unsigned int)u) << 16;
    return __builtin_bit_cast(float, v);
}
__device__ __forceinline__ u16 f2b(float f) {
    unsigned int x = __builtin_bit_cast(unsigned int, f);
    return (u16)((x + 0x7FFFu + ((x >> 16) & 1u)) >> 16);   // RNE
}

// ---------------- fp32 -> bf16 bulk convert ----------------
__global__ __launch_bounds__(256) void convert_bf16(const float* __restrict__ in,
                                                    u16* __restrict__ out, int n4)
{
    const int i = blockIdx.x * 256 + threadIdx.x;
    if (i >= n4) return;
    const float4 v = ((const float4*)in)[i];
    u16 o[4] = { f2b(v.x), f2b(v.y), f2b(v.z), f2b(v.w) };
    ((ushort4*)out)[i] = *(ushort4*)o;
}

// ------- pack [Wr | Wt] into bf16 [HD][2K] (contiguous k per output row) -------
__global__ __launch_bounds__(256) void pack_weights(const float* __restrict__ wr,
    const float* __restrict__ wt, u16* __restrict__ out, int K)
{
    const int idx = blockIdx.x * 256 + threadIdx.x;
    const int total = HD * 2 * K;
    if (idx >= total) return;
    const int h = idx / (2 * K);
    const int kc = idx - h * 2 * K;
    const float v = (kc < K) ? wr[(size_t)h * K + kc] : wt[(size_t)h * K + kc - K];
    out[idx] = f2b(v);
}

// ---------------- CSR build ----------------
__global__ __launch_bounds__(256) void hist_kernel(const int* __restrict__ dst,
                                                   int* __restrict__ deg, int E)
{
    const int e = blockIdx.x * 256 + threadIdx.x;
    if (e < E) atomicAdd(&deg[dst[e]], 1);
}

__global__ __launch_bounds__(1024) void scan_kernel(const int* __restrict__ deg,
                                                    int* __restrict__ rowptr, int N)
{
    __shared__ int sums[1024];
    const int t = threadIdx.x;
    const int C = (N + 1023) >> 10;
    const int lo = t * C;
    const int hi = (lo + C < N) ? (lo + C) : N;
    int s = 0;
    for (int i = lo; i < hi; ++i) s += deg[i];
    sums[t] = s;
    __syncthreads();
    for (int off = 1; off < 1024; off <<= 1) {
        int u = (t >= off) ? sums[t - off] : 0;
        __syncthreads();
        sums[t] += u;
        __syncthreads();
    }
    int run = (t == 0) ? 0 : sums[t - 1];
    for (int i = lo; i < hi; ++i) { rowptr[i] = run; run += deg[i]; }
    if (t == 1023) rowptr[N] = run;
}

__global__ __launch_bounds__(256) void fill_kernel(const int* __restrict__ src,
    const int* __restrict__ dst, const int* __restrict__ rowptr,
    int* __restrict__ cursor, int* __restrict__ eidx, int E)
{
    const int e = blockIdx.x * 256 + threadIdx.x;
    if (e >= E) return;
    const int d = dst[e];
    const int p = atomicAdd(&cursor[d], 1);
    eidx[rowptr[d] + p] = src[e];
}

// ------- CSR gather: aggb[n] = bf16( (1/S) * sum_int q(h[s]) ) -------
// int accumulation -> order-independent -> deterministic. blockDim = FD.
template<int FD>
__global__ __launch_bounds__(192) void gather_kernel(
    const u16* __restrict__ h, const int* __restrict__ rowptr,
    const int* __restrict__ eidx, u16* __restrict__ aggb, int N)
{
    const int t = threadIdx.x;
    for (int n = blockIdx.x; n < N; n += gridDim.x) {
        const int beg = rowptr[n], end = rowptr[n + 1];
        int acc = 0;
        int j = beg;
        for (; j + 1 < end; j += 2) {
            const int s0 = eidx[j], s1 = eidx[j + 1];
            acc += __float2int_rn(b2f(h[(size_t)s0 * FD + t]) * AGG_S)
                 + __float2int_rn(b2f(h[(size_t)s1 * FD + t]) * AGG_S);
        }
        if (j < end)
            acc += __float2int_rn(b2f(h[(size_t)eidx[j] * FD + t]) * AGG_S);
        aggb[(size_t)n * FD + t] = f2b((float)acc * AGG_IS);
    }
}

// -------- MFMA GEMM: Hpre = [A1|A2] @ Wb^T + bias ; BN sum/sumsq ----------
// 256 thr = 4 waves; block tile 64 rows x 192 cols; wave = 16 rows x 12 col-frags.
// A-frag: lane holds row (lane&15), k = kk + (lane>>4)*8 + j  (16B load)
// B-frag: lane holds col (lane&15), same k slots from Wb[col][k] (16B load, L2-hot)
template<int K1, int K2>
__global__ __launch_bounds__(256) void gemm_mfma(
    const u16* __restrict__ A1, const u16* __restrict__ A2,
    const u16* __restrict__ Wb, const float* __restrict__ bias,
    u16* __restrict__ Hout, long long* __restrict__ statsq, int N)
{
    constexpr int KC = K1 + K2;
    __shared__ float red[2][16][HD];
    const int tid  = threadIdx.x;
    const int wave = tid >> 6, lane = tid & 63;
    const int c    = lane & 15, kg = lane >> 4;
    const int row0 = blockIdx.x * 64 + wave * 16;
    const int arow = row0 + c;
    const int arc  = arow < N ? arow : N - 1;

    f32x4 acc[12];
#pragma unroll
    for (int f = 0; f < 12; ++f) acc[f] = (f32x4){0.f, 0.f, 0.f, 0.f};

    const u16* a1p = A1 + (size_t)arc * K1 + kg * 8;
    const u16* a2p = A2 + (size_t)arc * K2 + kg * 8;

#pragma unroll
    for (int kk = 0; kk < KC; kk += 32) {
        const bf16x8 a = (kk < K1) ? *(const bf16x8*)(a1p + kk)
                                   : *(const bf16x8*)(a2p + (kk - K1));
#pragma unroll
        for (int f = 0; f < 12; ++f) {
            const bf16x8 b = *(const bf16x8*)(Wb + (size_t)(f * 16 + c) * KC + kk + kg * 8);
            acc[f] = __builtin_amdgcn_mfma_f32_16x16x32_bf16(a, b, acc[f], 0, 0, 0);
        }
    }

    // epilogue: D col = f*16 + (lane&15), row = row0 + kg*4 + r
    float s1v[12], s2v[12];
#pragma unroll
    for (int f = 0; f < 12; ++f) { s1v[f] = 0.f; s2v[f] = 0.f; }

#pragma unroll
    for (int f = 0; f < 12; ++f) {
        const int col = f * 16 + c;
        const float bv = bias[col];
#pragma unroll
        for (int r = 0; r < 4; ++r) {
            const int orow = row0 + kg * 4 + r;
            if (orow < N) {
                const float v = acc[f][r] + bv;
                s1v[f] += v;
                s2v[f] += v * v;
                Hout[(size_t)orow * HD + col] = f2b(v);
            }
        }
    }

    const int lrow = wave * 4 + kg;   // 0..15
#pragma unroll
    for (int f = 0; f < 12; ++f) {
        red[0][lrow][f * 16 + c] = s1v[f];
        red[1][lrow][f * 16 + c] = s2v[f];
    }
    __syncthreads();
    if (tid < HD) {
        float a1 = 0.f, a2 = 0.f;
#pragma unroll
        for (int r = 0; r < 16; ++r) { a1 += red[0][r][tid]; a2 += red[1][r][tid]; }
        atomicAdd((unsigned long long*)&statsq[tid],
                  (unsigned long long)(long long)llrintf(a1 * STAT_S));
        atomicAdd((unsigned long long*)&statsq[HD + tid],
                  (unsigned long long)(long long)llrintf(a2 * STAT_S));
    }
}

// ---------------- BN: scale/shift from fixed-point sum/sumsq ----------------
__global__ void stats_finalize(const long long* __restrict__ statsq,
    const float* __restrict__ gamma, const float* __restrict__ beta,
    float* __restrict__ scsh, int N)
{
    const int c = threadIdx.x;
    if (c >= HD) return;
    const float inv = 1.0f / (float)N;
    const float sum   = (float)statsq[c] * STAT_IS;
    const float sumsq = (float)statsq[HD + c] * STAT_IS;
    const float mu  = sum * inv;
    const float var = sumsq * inv - mu * mu;
    const float sc  = gamma[c] * rsqrtf(var + BNEPS);
    scsh[c]      = sc;
    scsh[HD + c] = beta[c] - mu * sc;
}

// ---------------- h = relu(hpre*scale + shift), bf16 in/out ----------------
__global__ __launch_bounds__(256) void norm_relu(const u16* __restrict__ hpre,
    u16* __restrict__ h, const float* __restrict__ scsh, int N)
{
    const int idx = blockIdx.x * 256 + threadIdx.x;   // 8-elem granule
    const int total = N * (HD / 8);
    if (idx >= total) return;
    const int c8 = idx % (HD / 8);
    const uint4 packed = ((const uint4*)hpre)[idx];
    const u16* pu = (const u16*)&packed;
    const float* sc = scsh + c8 * 8;
    const float* sh = scsh + HD + c8 * 8;
    u16 o[8];
#pragma unroll
    for (int j = 0; j < 8; ++j)
        o[j] = f2b(fmaxf(0.f, fmaf(b2f(pu[j]), sc[j], sh[j])));
    ((uint4*)h)[idx] = *(uint4*)o;
}

// ------- fused mean-pool (deterministic segment sum) + MLP head ----------
__global__ __launch_bounds__(192) void pool_head_kernel(
    const u16* __restrict__ h, const int* __restrict__ batch, int N,
    const float* __restrict__ w1, const float* __restrict__ b1,
    const float* __restrict__ w2, const float* __restrict__ b2,
    const float* __restrict__ ow, const float* __restrict__ ob,
    float* __restrict__ out)
{
    __shared__ float gv[HD];
    __shared__ float h1[HD];
    __shared__ float h2[HD];
    const int g = blockIdx.x;
    const int t = threadIdx.x;

    int lo = 0, hi = N;
    while (lo < hi) { int m = (lo + hi) >> 1; if (batch[m] < g) lo = m + 1; else hi = m; }
    const int start = lo;
    hi = N;
    while (lo < hi) { int m = (lo + hi) >> 1; if (batch[m] < g + 1) lo = m + 1; else hi = m; }
    const int end = lo;

    float s = 0.f;
    for (int r = start; r < end; ++r) s += b2f(h[(size_t)r * HD + t]);
    const float cnt = fmaxf((float)(end - start), 1.0f);
    gv[t] = s / cnt;
    __syncthreads();
    {
        float acc = b1[t];
        const float* wr = w1 + (size_t)t * HD;
#pragma unroll 4
        for (int k = 0; k < HD; ++k) acc = fmaf(gv[k], wr[k], acc);
        h1[t] = fmaxf(acc, 0.f);
    }
    __syncthreads();
    {
        float acc = b2[t];
        const float* wr = w2 + (size_t)t * HD;
#pragma unroll 4
        for (int k = 0; k < HD; ++k) acc = fmaf(h1[k], wr[k], acc);
        h2[t] = acc * ow[t];
    }
    __syncthreads();
    if (t == 0) {
        float acc = ob[0];
        for (int k = 0; k < HD; ++k) acc += h2[k];
        out[g] = acc;
    }
}

extern "C" void kernel_launch(void* const* d_in, const int* in_sizes, int n_in,
                              void* d_out, int out_size, void* d_ws, size_t ws_size,
                              hipStream_t stream)
{
    const float* x       = (const float*)d_in[0];
    const int*   ei      = (const int*)d_in[1];
    const int*   batch   = (const int*)d_in[2];
    const float* w_rel0  = (const float*)d_in[4];
    const float* b_rel0  = (const float*)d_in[5];
    const float* w_root0 = (const float*)d_in[6];
    const float* w_rel   = (const float*)d_in[7];
    const float* b_rel   = (const float*)d_in[8];
    const float* w_root  = (const float*)d_in[9];
    const float* bn_g    = (const float*)d_in[10];
    const float* bn_b    = (const float*)d_in[11];
    const float* hw1     = (const float*)d_in[12];
    const float* hb1     = (const float*)d_in[13];
    const float* hw2     = (const float*)d_in[14];
    const float* hb2     = (const float*)d_in[15];
    const float* ow      = (const float*)d_in[16];
    const float* ob      = (const float*)d_in[17];
    float* out = (float*)d_out;

    const int N = in_sizes[0] / FD0;
    const int E = in_sizes[1] / 2;
    const int* src = ei;
    const int* dst = ei + E;

    char* ws = (char*)d_ws;
    size_t off = 0;
    u16* xb   = (u16*)(ws + off); off += (size_t)N * FD0 * 2;     // x bf16
    u16* hb   = (u16*)(ws + off); off += (size_t)N * HD * 2;      // h bf16
    u16* aggb = (u16*)(ws + off); off += (size_t)N * HD * 2;      // agg bf16
    u16* hpre = (u16*)(ws + off); off += (size_t)N * HD * 2;      // pre-BN bf16
    u16* wp0  = (u16*)(ws + off); off += (size_t)HD * 2 * FD0 * 2;    // layer0 weights
    u16* wp123= (u16*)(ws + off); off += (size_t)3 * HD * 2 * HD * 2; // layer1-3 weights
    off = (off + 15) & ~(size_t)15;
    long long* statsq = (long long*)(ws + off); off += 2 * HD * sizeof(long long);
    float*     scsh   = (float*)(ws + off);     off += 2 * HD * sizeof(float);
    int*       rowptr = (int*)(ws + off);       off += (size_t)(N + 1) * 4;
    int*       deg    = (int*)(ws + off);       off += (size_t)N * 4;
    int*       eidx   = (int*)(ws + off);       off += (size_t)E * 4;

    const dim3 b256(256), b192(192);

    // ---- conversions & CSR build (independent prep)
    convert_bf16<<<idiv(N * FD0 / 4, 256), b256, 0, stream>>>(x, xb, N * FD0 / 4);
    pack_weights<<<idiv(HD * 2 * FD0, 256), b256, 0, stream>>>(w_rel0, w_root0, wp0, FD0);
    for (int i = 0; i < 3; ++i)
        pack_weights<<<idiv(HD * 2 * HD, 256), b256, 0, stream>>>(
            w_rel + (size_t)i * HD * HD, w_root + (size_t)i * HD * HD,
            wp123 + (size_t)i * HD * 2 * HD, HD);
    hipMemsetAsync(deg, 0, (size_t)N * sizeof(int), stream);
    hist_kernel<<<idiv(E, 256), b256, 0, stream>>>(dst, deg, E);
    scan_kernel<<<1, 1024, 0, stream>>>(deg, rowptr, N);
    hipMemsetAsync(deg, 0, (size_t)N * sizeof(int), stream);
    fill_kernel<<<idiv(E, 256), b256, 0, stream>>>(src, dst, rowptr, deg, eidx, E);

    // ---- layer 0 (K=128+128)
    hipMemsetAsync(statsq, 0, 2 * HD * sizeof(long long), stream);
    gather_kernel<FD0><<<N, dim3(FD0), 0, stream>>>(xb, rowptr, eidx, aggb, N);
    gemm_mfma<FD0, FD0><<<idiv(N, 64), b256, 0, stream>>>(aggb, xb, wp0, b_rel0,
                                                          hpre, statsq, N);
    stats_finalize<<<1, b192, 0, stream>>>(statsq, bn_g, bn_b, scsh, N);
    norm_relu<<<idiv(N * (HD / 8), 256), b256, 0, stream>>>(hpre, hb, scsh, N);

    // ---- layers 1..3 (K=192+192)
    for (int i = 0; i < 3; ++i) {
        hipMemsetAsync(statsq, 0, 2 * HD * sizeof(long long), stream);
        gather_kernel<HD><<<N, b192, 0, stream>>>(hb, rowptr, eidx, aggb, N);
        gemm_mfma<HD, HD><<<idiv(N, 64), b256, 0, stream>>>(
            aggb, hb, wp123 + (size_t)i * HD * 2 * HD,
            b_rel + (size_t)i * HD, hpre, statsq, N);
        stats_finalize<<<1, b192, 0, stream>>>(statsq, bn_g + (size_t)(i + 1) * HD,
                                               bn_b + (size_t)(i + 1) * HD, scsh, N);
        norm_relu<<<idiv(N * (HD / 8), 256), b256, 0, stream>>>(hpre, hb, scsh, N);
    }

    // ---- fused global mean pool + head
    pool_head_kernel<<<NG, b192, 0, stream>>>(hb, batch, N, hw1, hb1, hw2, hb2,
                                              ow, ob, out);
}

// Round 7
// 619.488 us; speedup vs baseline: 2.4440x; 1.3161x over previous
//
#include <hip/hip_runtime.h>

#define HD 192
#define FD0 128
#define NG 256
#define BNEPS 1e-5f

#define AGG_S   2097152.0f        // 2^21 fixed-point scale for aggregation
#define AGG_IS  (1.0f / 2097152.0f)
#define STAT_S  1048576.0f        // 2^20 fixed-point scale for BN stats
#define STAT_IS (1.0f / 1048576.0f)

typedef unsigned short u16;
typedef __attribute__((ext_vector_type(8))) short bf16x8;
typedef __attribute__((ext_vector_type(4))) float f32x4;

static inline int idiv(int a, int b) { return (a + b - 1) / b; }

__device__ __forceinline__ float b2f(u16 u) {
    unsigned int v = ((unsigned int)u) << 16;
    return __builtin_bit_cast(float, v);
}
__device__ __forceinline__ u16 f2b(float f) {
    unsigned int x = __builtin_bit_cast(unsigned int, f);
    return (u16)((x + 0x7FFFu + ((x >> 16) & 1u)) >> 16);   // RNE
}

// async global->LDS, 16B per lane; LDS dest = uniform base + lane*16
__device__ __forceinline__ void async_cp16(const void* g, void* l) {
    __builtin_amdgcn_global_load_lds(
        (const __attribute__((address_space(1))) unsigned int*)g,
        (__attribute__((address_space(3))) unsigned int*)l, 16, 0, 0);
}

// ---------------- fp32 -> bf16 bulk convert ----------------
__global__ __launch_bounds__(256) void convert_bf16(const float* __restrict__ in,
                                                    u16* __restrict__ out, int n4)
{
    const int i = blockIdx.x * 256 + threadIdx.x;
    if (i >= n4) return;
    const float4 v = ((const float4*)in)[i];
    u16 o[4] = { f2b(v.x), f2b(v.y), f2b(v.z), f2b(v.w) };
    ((ushort4*)out)[i] = *(ushort4*)o;
}

// ------- pack [Wr | Wt] bf16 in MFMA-frag chunk order ------------------------
// out elem idx = ((chunk*768 + fglob*64 + kg*16 + c) * 8 + j)
//   col = fglob*16 + c ; k = chunk*32 + kg*8 + j ; value = k<K ? wr[col][k] : wt[col][k-K]
__global__ __launch_bounds__(256) void pack_weights(const float* __restrict__ wr,
    const float* __restrict__ wt, u16* __restrict__ out, int K)
{
    const int idx = blockIdx.x * 256 + threadIdx.x;
    const int total = HD * 2 * K;
    if (idx >= total) return;
    const int j  = idx & 7;
    const int t  = idx >> 3;
    const int c  = t & 15;
    const int kg = (t >> 4) & 3;
    const int rest = t >> 6;
    const int fglob = rest % 12;
    const int chunk = rest / 12;
    const int col = fglob * 16 + c;
    const int k   = chunk * 32 + kg * 8 + j;
    const float v = (k < K) ? wr[(size_t)col * K + k] : wt[(size_t)col * K + (k - K)];
    out[idx] = f2b(v);
}

// ---------------- CSR build ----------------
__global__ __launch_bounds__(256) void hist_kernel(const int* __restrict__ dst,
                                                   int* __restrict__ deg, int E)
{
    const int e = blockIdx.x * 256 + threadIdx.x;
    if (e < E) atomicAdd(&deg[dst[e]], 1);
}

__global__ __launch_bounds__(1024) void scan_kernel(const int* __restrict__ deg,
                                                    int* __restrict__ rowptr, int N)
{
    __shared__ int sums[1024];
    const int t = threadIdx.x;
    const int C = (N + 1023) >> 10;
    const int lo = t * C;
    const int hi = (lo + C < N) ? (lo + C) : N;
    int s = 0;
    for (int i = lo; i < hi; ++i) s += deg[i];
    sums[t] = s;
    __syncthreads();
    for (int off = 1; off < 1024; off <<= 1) {
        int u = (t >= off) ? sums[t - off] : 0;
        __syncthreads();
        sums[t] += u;
        __syncthreads();
    }
    int run = (t == 0) ? 0 : sums[t - 1];
    for (int i = lo; i < hi; ++i) { rowptr[i] = run; run += deg[i]; }
    if (t == 1023) rowptr[N] = run;
}

__global__ __launch_bounds__(256) void fill_kernel(const int* __restrict__ src,
    const int* __restrict__ dst, const int* __restrict__ rowptr,
    int* __restrict__ cursor, int* __restrict__ eidx, int E)
{
    const int e = blockIdx.x * 256 + threadIdx.x;
    if (e >= E) return;
    const int d = dst[e];
    const int p = atomicAdd(&cursor[d], 1);
    eidx[rowptr[d] + p] = src[e];
}

// ------- CSR gather: aggb[n] = bf16( (1/S) * sum_int q(h[s]) ) -------
template<int FD>
__global__ __launch_bounds__(192) void gather_kernel(
    const u16* __restrict__ h, const int* __restrict__ rowptr,
    const int* __restrict__ eidx, u16* __restrict__ aggb, int N)
{
    const int t = threadIdx.x;
    for (int n = blockIdx.x; n < N; n += gridDim.x) {
        const int beg = rowptr[n], end = rowptr[n + 1];
        int acc = 0;
        int j = beg;
        for (; j + 1 < end; j += 2) {
            const int s0 = eidx[j], s1 = eidx[j + 1];
            acc += __float2int_rn(b2f(h[(size_t)s0 * FD + t]) * AGG_S)
                 + __float2int_rn(b2f(h[(size_t)s1 * FD + t]) * AGG_S);
        }
        if (j < end)
            acc += __float2int_rn(b2f(h[(size_t)eidx[j] * FD + t]) * AGG_S);
        aggb[(size_t)n * FD + t] = f2b((float)acc * AGG_IS);
    }
}

// -------- MFMA GEMM: Hpre = [A1|A2] @ Wb^T + bias ; BN sum/sumsq --------------
// 256 thr = 4 waves in 2x2; block tile 64 rows x 192 cols; wave = 32r x 96c.
// B staged per 32-k chunk into LDS (frag order, double-buffered, global_load_lds).
// A-frags prefetched one chunk ahead in registers.
template<int K1, int K2>
__global__ __launch_bounds__(256, 3) void gemm_mfma(
    const u16* __restrict__ A1, const u16* __restrict__ A2,
    const u16* __restrict__ Wb, const float* __restrict__ bias,
    u16* __restrict__ Hout, long long* __restrict__ statsq, int N)
{
    constexpr int KC = K1 + K2;
    constexpr int NC = KC / 32;
    __shared__ u16 bb[2][6144];     // 2 x 12KB chunk buffers (also reused as red)

    const int tid  = threadIdx.x;
    const int wave = tid >> 6, lane = tid & 63;
    const int c    = lane & 15, kg = lane >> 4;
    const int rw   = wave >> 1, cw = wave & 1;
    const int row0 = blockIdx.x * 64;

    int arc[2];
#pragma unroll
    for (int m = 0; m < 2; ++m) {
        const int r = row0 + rw * 32 + m * 16 + c;
        arc[m] = r < N ? r : N - 1;
    }

    f32x4 acc[2][6];
#pragma unroll
    for (int m = 0; m < 2; ++m)
#pragma unroll
        for (int f = 0; f < 6; ++f) acc[m][f] = (f32x4){0.f, 0.f, 0.f, 0.f};

    // stage chunk -> bb[buf]: wave handles 1536 ushorts (3 x 1KB async copies)
    auto stage = [&](int chunk, int buf) {
        const u16* g = Wb + (size_t)chunk * 6144 + wave * 1536 + lane * 8;
        u16* l = &bb[buf][wave * 1536];
#pragma unroll
        for (int i = 0; i < 3; ++i)
            async_cp16(g + i * 512, l + i * 512);
    };
    auto loadA = [&](int chunk, bf16x8* dst) {
        const int kk = chunk * 32;
#pragma unroll
        for (int m = 0; m < 2; ++m) {
            const u16* p = (kk < K1)
                ? A1 + (size_t)arc[m] * K1 + kk + kg * 8
                : A2 + (size_t)arc[m] * K2 + (kk - K1) + kg * 8;
            dst[m] = *(const bf16x8*)p;
        }
    };

    bf16x8 a_cur[2], a_nxt[2];
    stage(0, 0);
    loadA(0, a_cur);
    __syncthreads();

#pragma unroll
    for (int ch = 0; ch < NC; ++ch) {
        const int cb = ch & 1;
        if (ch + 1 < NC) {
            stage(ch + 1, cb ^ 1);
            loadA(ch + 1, a_nxt);
        }
#pragma unroll
        for (int f = 0; f < 6; ++f) {
            const int fglob = cw * 6 + f;
            const bf16x8 b = *(const bf16x8*)&bb[cb][(fglob * 64 + kg * 16 + c) * 8];
            acc[0][f] = __builtin_amdgcn_mfma_f32_16x16x32_bf16(a_cur[0], b, acc[0][f], 0, 0, 0);
            acc[1][f] = __builtin_amdgcn_mfma_f32_16x16x32_bf16(a_cur[1], b, acc[1][f], 0, 0, 0);
        }
        __syncthreads();
        a_cur[0] = a_nxt[0]; a_cur[1] = a_nxt[1];
    }

    // ---- epilogue: bias + store + BN partial sums ----
    float s1v[6], s2v[6];
#pragma unroll
    for (int f = 0; f < 6; ++f) { s1v[f] = 0.f; s2v[f] = 0.f; }

#pragma unroll
    for (int f = 0; f < 6; ++f) {
        const int col = cw * 96 + f * 16 + c;
        const float bv = bias[col];
#pragma unroll
        for (int m = 0; m < 2; ++m)
#pragma unroll
            for (int r = 0; r < 4; ++r) {
                const int orow = row0 + rw * 32 + m * 16 + kg * 4 + r;
                if (orow < N) {
                    const float v = acc[m][f][r] + bv;
                    s1v[f] += v;
                    s2v[f] += v * v;
                    Hout[(size_t)orow * HD + col] = f2b(v);
                }
            }
    }
    // reduce over kg (lanes xor 16, 32): same col, different rows
#pragma unroll
    for (int f = 0; f < 6; ++f) {
        s1v[f] += __shfl_xor(s1v[f], 16); s1v[f] += __shfl_xor(s1v[f], 32);
        s2v[f] += __shfl_xor(s2v[f], 16); s2v[f] += __shfl_xor(s2v[f], 32);
    }
    float* red = (float*)&bb[0][0];          // 768 floats, staged buffers are dead
    if (kg == 0) {
#pragma unroll
        for (int f = 0; f < 6; ++f) {
            const int col = cw * 96 + f * 16 + c;
            red[rw * 192 + col]       = s1v[f];
            red[384 + rw * 192 + col] = s2v[f];
        }
    }
    __syncthreads();
    if (tid < HD) {
        const float a1 = red[tid] + red[192 + tid];
        const float a2 = red[384 + tid] + red[576 + tid];
        atomicAdd((unsigned long long*)&statsq[tid],
                  (unsigned long long)(long long)llrintf(a1 * STAT_S));
        atomicAdd((unsigned long long*)&statsq[HD + tid],
                  (unsigned long long)(long long)llrintf(a2 * STAT_S));
    }
}

// ---------------- BN: scale/shift from fixed-point sum/sumsq ----------------
__global__ void stats_finalize(const long long* __restrict__ statsq,
    const float* __restrict__ gamma, const float* __restrict__ beta,
    float* __restrict__ scsh, int N)
{
    const int c = threadIdx.x;
    if (c >= HD) return;
    const float inv = 1.0f / (float)N;
    const float sum   = (float)statsq[c] * STAT_IS;
    const float sumsq = (float)statsq[HD + c] * STAT_IS;
    const float mu  = sum * inv;
    const float var = sumsq * inv - mu * mu;
    const float sc  = gamma[c] * rsqrtf(var + BNEPS);
    scsh[c]      = sc;
    scsh[HD + c] = beta[c] - mu * sc;
}

// ---------------- h = relu(hpre*scale + shift), bf16 in/out ----------------
__global__ __launch_bounds__(256) void norm_relu(const u16* __restrict__ hpre,
    u16* __restrict__ h, const float* __restrict__ scsh, int N)
{
    const int idx = blockIdx.x * 256 + threadIdx.x;   // 8-elem granule
    const int total = N * (HD / 8);
    if (idx >= total) return;
    const int c8 = idx % (HD / 8);
    const uint4 packed = ((const uint4*)hpre)[idx];
    const u16* pu = (const u16*)&packed;
    const float* sc = scsh + c8 * 8;
    const float* sh = scsh + HD + c8 * 8;
    u16 o[8];
#pragma unroll
    for (int j = 0; j < 8; ++j)
        o[j] = f2b(fmaxf(0.f, fmaf(b2f(pu[j]), sc[j], sh[j])));
    ((uint4*)h)[idx] = *(uint4*)o;
}

// ------- fused mean-pool (deterministic segment sum) + MLP head ----------
__global__ __launch_bounds__(192) void pool_head_kernel(
    const u16* __restrict__ h, const int* __restrict__ batch, int N,
    const float* __restrict__ w1, const float* __restrict__ b1,
    const float* __restrict__ w2, const float* __restrict__ b2,
    const float* __restrict__ ow, const float* __restrict__ ob,
    float* __restrict__ out)
{
    __shared__ float gv[HD];
    __shared__ float h1[HD];
    __shared__ float h2[HD];
    const int g = blockIdx.x;
    const int t = threadIdx.x;

    int lo = 0, hi = N;
    while (lo < hi) { int m = (lo + hi) >> 1; if (batch[m] < g) lo = m + 1; else hi = m; }
    const int start = lo;
    hi = N;
    while (lo < hi) { int m = (lo + hi) >> 1; if (batch[m] < g + 1) lo = m + 1; else hi = m; }
    const int end = lo;

    float s = 0.f;
    for (int r = start; r < end; ++r) s += b2f(h[(size_t)r * HD + t]);
    const float cnt = fmaxf((float)(end - start), 1.0f);
    gv[t] = s / cnt;
    __syncthreads();
    {
        float acc = b1[t];
        const float* wr = w1 + (size_t)t * HD;
#pragma unroll 4
        for (int k = 0; k < HD; ++k) acc = fmaf(gv[k], wr[k], acc);
        h1[t] = fmaxf(acc, 0.f);
    }
    __syncthreads();
    {
        float acc = b2[t];
        const float* wr = w2 + (size_t)t * HD;
#pragma unroll 4
        for (int k = 0; k < HD; ++k) acc = fmaf(h1[k], wr[k], acc);
        h2[t] = acc * ow[t];
    }
    __syncthreads();
    if (t == 0) {
        float acc = ob[0];
        for (int k = 0; k < HD; ++k) acc += h2[k];
        out[g] = acc;
    }
}

extern "C" void kernel_launch(void* const* d_in, const int* in_sizes, int n_in,
                              void* d_out, int out_size, void* d_ws, size_t ws_size,
                              hipStream_t stream)
{
    const float* x       = (const float*)d_in[0];
    const int*   ei      = (const int*)d_in[1];
    const int*   batch   = (const int*)d_in[2];
    const float* w_rel0  = (const float*)d_in[4];
    const float* b_rel0  = (const float*)d_in[5];
    const float* w_root0 = (const float*)d_in[6];
    const float* w_rel   = (const float*)d_in[7];
    const float* b_rel   = (const float*)d_in[8];
    const float* w_root  = (const float*)d_in[9];
    const float* bn_g    = (const float*)d_in[10];
    const float* bn_b    = (const float*)d_in[11];
    const float* hw1     = (const float*)d_in[12];
    const float* hb1     = (const float*)d_in[13];
    const float* hw2     = (const float*)d_in[14];
    const float* hb2     = (const float*)d_in[15];
    const float* ow      = (const float*)d_in[16];
    const float* ob      = (const float*)d_in[17];
    float* out = (float*)d_out;

    const int N = in_sizes[0] / FD0;
    const int E = in_sizes[1] / 2;
    const int* src = ei;
    const int* dst = ei + E;

    char* ws = (char*)d_ws;
    size_t off = 0;
    u16* xb   = (u16*)(ws + off); off += (size_t)N * FD0 * 2;     // x bf16
    u16* hb   = (u16*)(ws + off); off += (size_t)N * HD * 2;      // h bf16
    u16* aggb = (u16*)(ws + off); off += (size_t)N * HD * 2;      // agg bf16
    u16* hpre = (u16*)(ws + off); off += (size_t)N * HD * 2;      // pre-BN bf16
    u16* wp0  = (u16*)(ws + off); off += (size_t)HD * 2 * FD0 * 2;    // layer0 weights
    u16* wp123= (u16*)(ws + off); off += (size_t)3 * HD * 2 * HD * 2; // layer1-3 weights
    off = (off + 15) & ~(size_t)15;
    long long* statsq = (long long*)(ws + off); off += 2 * HD * sizeof(long long);
    float*     scsh   = (float*)(ws + off);     off += 2 * HD * sizeof(float);
    int*       rowptr = (int*)(ws + off);       off += (size_t)(N + 1) * 4;
    int*       deg    = (int*)(ws + off);       off += (size_t)N * 4;
    int*       eidx   = (int*)(ws + off);       off += (size_t)E * 4;

    const dim3 b256(256), b192(192);

    // ---- conversions & CSR build (independent prep)
    convert_bf16<<<idiv(N * FD0 / 4, 256), b256, 0, stream>>>(x, xb, N * FD0 / 4);
    pack_weights<<<idiv(HD * 2 * FD0, 256), b256, 0, stream>>>(w_rel0, w_root0, wp0, FD0);
    for (int i = 0; i < 3; ++i)
        pack_weights<<<idiv(HD * 2 * HD, 256), b256, 0, stream>>>(
            w_rel + (size_t)i * HD * HD, w_root + (size_t)i * HD * HD,
            wp123 + (size_t)i * HD * 2 * HD, HD);
    hipMemsetAsync(deg, 0, (size_t)N * sizeof(int), stream);
    hist_kernel<<<idiv(E, 256), b256, 0, stream>>>(dst, deg, E);
    scan_kernel<<<1, 1024, 0, stream>>>(deg, rowptr, N);
    hipMemsetAsync(deg, 0, (size_t)N * sizeof(int), stream);
    fill_kernel<<<idiv(E, 256), b256, 0, stream>>>(src, dst, rowptr, deg, eidx, E);

    // ---- layer 0 (K=128+128)
    hipMemsetAsync(statsq, 0, 2 * HD * sizeof(long long), stream);
    gather_kernel<FD0><<<N, dim3(FD0), 0, stream>>>(xb, rowptr, eidx, aggb, N);
    gemm_mfma<FD0, FD0><<<idiv(N, 64), b256, 0, stream>>>(aggb, xb, wp0, b_rel0,
                                                          hpre, statsq, N);
    stats_finalize<<<1, b192, 0, stream>>>(statsq, bn_g, bn_b, scsh, N);
    norm_relu<<<idiv(N * (HD / 8), 256), b256, 0, stream>>>(hpre, hb, scsh, N);

    // ---- layers 1..3 (K=192+192)
    for (int i = 0; i < 3; ++i) {
        hipMemsetAsync(statsq, 0, 2 * HD * sizeof(long long), stream);
        gather_kernel<HD><<<N, b192, 0, stream>>>(hb, rowptr, eidx, aggb, N);
        gemm_mfma<HD, HD><<<idiv(N, 64), b256, 0, stream>>>(
            aggb, hb, wp123 + (size_t)i * HD * 2 * HD,
            b_rel + (size_t)i * HD, hpre, statsq, N);
        stats_finalize<<<1, b192, 0, stream>>>(statsq, bn_g + (size_t)(i + 1) * HD,
                                               bn_b + (size_t)(i + 1) * HD, scsh, N);
        norm_relu<<<idiv(N * (HD / 8), 256), b256, 0, stream>>>(hpre, hb, scsh, N);
    }

    // ---- fused global mean pool + head
    pool_head_kernel<<<NG, b192, 0, stream>>>(hb, batch, N, hw1, hb1, hw2, hb2,
                                              ow, ob, out);
}

// Round 8
// 520.649 us; speedup vs baseline: 2.9079x; 1.1898x over previous
//
#include <hip/hip_runtime.h>

#define HD 192
#define FD0 128
#define NG 256
#define BNEPS 1e-5f

#define AGG_S   2097152.0f        // 2^21 fixed-point scale for aggregation
#define AGG_IS  (1.0f / 2097152.0f)
#define STAT_S  1048576.0f        // 2^20 fixed-point scale for BN stats
#define STAT_IS (1.0f / 1048576.0f)

typedef unsigned short u16;
typedef __attribute__((ext_vector_type(8))) short bf16x8;
typedef __attribute__((ext_vector_type(4))) float f32x4;

static inline int idiv(int a, int b) { return (a + b - 1) / b; }

__device__ __forceinline__ float b2f(u16 u) {
    unsigned int v = ((unsigned int)u) << 16;
    return __builtin_bit_cast(float, v);
}
__device__ __forceinline__ u16 f2b(float f) {
    unsigned int x = __builtin_bit_cast(unsigned int, f);
    return (u16)((x + 0x7FFFu + ((x >> 16) & 1u)) >> 16);   // RNE
}

// async global->LDS, 16B per lane; LDS dest = uniform base + lane*16
__device__ __forceinline__ void async_cp16(const void* g, void* l) {
    __builtin_amdgcn_global_load_lds(
        (const __attribute__((address_space(1))) unsigned int*)g,
        (__attribute__((address_space(3))) unsigned int*)l, 16, 0, 0);
}

// ---------------- fp32 -> bf16 bulk convert ----------------
__global__ __launch_bounds__(256) void convert_bf16(const float* __restrict__ in,
                                                    u16* __restrict__ out, int n4)
{
    const int i = blockIdx.x * 256 + threadIdx.x;
    if (i >= n4) return;
    const float4 v = ((const float4*)in)[i];
    u16 o[4] = { f2b(v.x), f2b(v.y), f2b(v.z), f2b(v.w) };
    ((ushort4*)out)[i] = *(ushort4*)o;
}

// ------- pack [Wr | Wt] bf16 in MFMA-frag chunk order ------------------------
__global__ __launch_bounds__(256) void pack_weights(const float* __restrict__ wr,
    const float* __restrict__ wt, u16* __restrict__ out, int K)
{
    const int idx = blockIdx.x * 256 + threadIdx.x;
    const int total = HD * 2 * K;
    if (idx >= total) return;
    const int j  = idx & 7;
    const int t  = idx >> 3;
    const int c  = t & 15;
    const int kg = (t >> 4) & 3;
    const int rest = t >> 6;
    const int fglob = rest % 12;
    const int chunk = rest / 12;
    const int col = fglob * 16 + c;
    const int k   = chunk * 32 + kg * 8 + j;
    const float v = (k < K) ? wr[(size_t)col * K + k] : wt[(size_t)col * K + (k - K)];
    out[idx] = f2b(v);
}

// ---------------- CSR build ----------------
__global__ __launch_bounds__(256) void hist_kernel(const int* __restrict__ dst,
                                                   int* __restrict__ deg, int E)
{
    const int e = blockIdx.x * 256 + threadIdx.x;
    if (e < E) atomicAdd(&deg[dst[e]], 1);
}

// hierarchical exclusive scan: partial sums -> scan sums -> expand
__global__ __launch_bounds__(256) void scan_partial(const int* __restrict__ deg,
                                                    int* __restrict__ psum, int N)
{
    __shared__ int s[256];
    const int t = threadIdx.x;
    const int i = blockIdx.x * 256 + t;
    s[t] = (i < N) ? deg[i] : 0;
    __syncthreads();
    for (int off = 128; off > 0; off >>= 1) {
        if (t < off) s[t] += s[t + off];
        __syncthreads();
    }
    if (t == 0) psum[blockIdx.x] = s[0];
}

__global__ __launch_bounds__(256) void scan_small(int* __restrict__ psum, int M)
{
    // M <= 256 (N <= 65536). exclusive scan in place.
    __shared__ int s[256];
    const int t = threadIdx.x;
    s[t] = (t < M) ? psum[t] : 0;
    __syncthreads();
    for (int off = 1; off < 256; off <<= 1) {
        const int u = (t >= off) ? s[t - off] : 0;
        __syncthreads();
        s[t] += u;
        __syncthreads();
    }
    if (t < M) psum[t] = (t == 0) ? 0 : s[t - 1];
}

__global__ __launch_bounds__(256) void scan_expand(const int* __restrict__ deg,
    const int* __restrict__ psum, int* __restrict__ rowptr, int N, int E)
{
    __shared__ int s[256];
    const int t = threadIdx.x;
    const int i = blockIdx.x * 256 + t;
    const int v = (i < N) ? deg[i] : 0;
    s[t] = v;
    __syncthreads();
    for (int off = 1; off < 256; off <<= 1) {
        const int u = (t >= off) ? s[t - off] : 0;
        __syncthreads();
        s[t] += u;
        __syncthreads();
    }
    if (i < N) rowptr[i] = psum[blockIdx.x] + s[t] - v;   // exclusive
    if (i == N - 1) rowptr[N] = E;
}

__global__ __launch_bounds__(256) void fill_kernel(const int* __restrict__ src,
    const int* __restrict__ dst, const int* __restrict__ rowptr,
    int* __restrict__ cursor, int* __restrict__ eidx, int E)
{
    const int e = blockIdx.x * 256 + threadIdx.x;
    if (e >= E) return;
    const int d = dst[e];
    const int p = atomicAdd(&cursor[d], 1);
    eidx[rowptr[d] + p] = src[e];
}

// ------- CSR gather: one WAVE per node; 2 edges/iter (half-wave each); -------
// lane o<FD/8 loads 16B (8 bf16 cols); int accumulation (deterministic);
// halves combined with shfl_xor(32); 16B stores.
template<int FD>
__global__ __launch_bounds__(256) void gather_kernel(
    const u16* __restrict__ h, const int* __restrict__ rowptr,
    const int* __restrict__ eidx, u16* __restrict__ aggb, int N)
{
    constexpr int OCT = FD / 8;
    const int wave = threadIdx.x >> 6;
    const int lane = threadIdx.x & 63;
    const int half = lane >> 5;
    const int o    = lane & 31;
    const int n    = blockIdx.x * 4 + wave;
    if (n >= N) return;
    const int beg = rowptr[n], end = rowptr[n + 1];
    const bool active = (o < OCT);

    int acc[8];
#pragma unroll
    for (int i = 0; i < 8; ++i) acc[i] = 0;

    for (int j = beg + half; j < end; j += 2) {
        if (active) {
            const int s = eidx[j];
            const uint4 pv = *(const uint4*)(h + (size_t)s * FD + o * 8);
            const u16* pu = (const u16*)&pv;
#pragma unroll
            for (int i = 0; i < 8; ++i)
                acc[i] += __float2int_rn(b2f(pu[i]) * AGG_S);
        }
    }
#pragma unroll
    for (int i = 0; i < 8; ++i) acc[i] += __shfl_xor(acc[i], 32);

    if (half == 0 && active) {
        u16 ov[8];
#pragma unroll
        for (int i = 0; i < 8; ++i) ov[i] = f2b((float)acc[i] * AGG_IS);
        *(uint4*)(aggb + (size_t)n * FD + o * 8) = *(uint4*)ov;
    }
}

// -------- MFMA GEMM: Hpre = [A1|A2] @ Wb^T + bias ; BN sum/sumsq --------------
template<int K1, int K2>
__global__ __launch_bounds__(256, 3) void gemm_mfma(
    const u16* __restrict__ A1, const u16* __restrict__ A2,
    const u16* __restrict__ Wb, const float* __restrict__ bias,
    u16* __restrict__ Hout, long long* __restrict__ statsq, int N)
{
    constexpr int KC = K1 + K2;
    constexpr int NC = KC / 32;
    __shared__ u16 bb[2][6144];     // 2 x 12KB chunk buffers (also reused as red)

    const int tid  = threadIdx.x;
    const int wave = tid >> 6, lane = tid & 63;
    const int c    = lane & 15, kg = lane >> 4;
    const int rw   = wave >> 1, cw = wave & 1;
    const int row0 = blockIdx.x * 64;

    int arc[2];
#pragma unroll
    for (int m = 0; m < 2; ++m) {
        const int r = row0 + rw * 32 + m * 16 + c;
        arc[m] = r < N ? r : N - 1;
    }

    f32x4 acc[2][6];
#pragma unroll
    for (int m = 0; m < 2; ++m)
#pragma unroll
        for (int f = 0; f < 6; ++f) acc[m][f] = (f32x4){0.f, 0.f, 0.f, 0.f};

    auto stage = [&](int chunk, int buf) {
        const u16* g = Wb + (size_t)chunk * 6144 + wave * 1536 + lane * 8;
        u16* l = &bb[buf][wave * 1536];
#pragma unroll
        for (int i = 0; i < 3; ++i)
            async_cp16(g + i * 512, l + i * 512);
    };
    auto loadA = [&](int chunk, bf16x8* dst) {
        const int kk = chunk * 32;
#pragma unroll
        for (int m = 0; m < 2; ++m) {
            const u16* p = (kk < K1)
                ? A1 + (size_t)arc[m] * K1 + kk + kg * 8
                : A2 + (size_t)arc[m] * K2 + (kk - K1) + kg * 8;
            dst[m] = *(const bf16x8*)p;
        }
    };

    bf16x8 a_cur[2], a_nxt[2];
    stage(0, 0);
    loadA(0, a_cur);
    __syncthreads();

#pragma unroll
    for (int ch = 0; ch < NC; ++ch) {
        const int cb = ch & 1;
        if (ch + 1 < NC) {
            stage(ch + 1, cb ^ 1);
            loadA(ch + 1, a_nxt);
        }
#pragma unroll
        for (int f = 0; f < 6; ++f) {
            const int fglob = cw * 6 + f;
            const bf16x8 b = *(const bf16x8*)&bb[cb][(fglob * 64 + kg * 16 + c) * 8];
            acc[0][f] = __builtin_amdgcn_mfma_f32_16x16x32_bf16(a_cur[0], b, acc[0][f], 0, 0, 0);
            acc[1][f] = __builtin_amdgcn_mfma_f32_16x16x32_bf16(a_cur[1], b, acc[1][f], 0, 0, 0);
        }
        __syncthreads();
        a_cur[0] = a_nxt[0]; a_cur[1] = a_nxt[1];
    }

    // ---- epilogue: bias + store + BN partial sums ----
    float s1v[6], s2v[6];
#pragma unroll
    for (int f = 0; f < 6; ++f) { s1v[f] = 0.f; s2v[f] = 0.f; }

#pragma unroll
    for (int f = 0; f < 6; ++f) {
        const int col = cw * 96 + f * 16 + c;
        const float bv = bias[col];
#pragma unroll
        for (int m = 0; m < 2; ++m)
#pragma unroll
            for (int r = 0; r < 4; ++r) {
                const int orow = row0 + rw * 32 + m * 16 + kg * 4 + r;
                if (orow < N) {
                    const float v = acc[m][f][r] + bv;
                    s1v[f] += v;
                    s2v[f] += v * v;
                    Hout[(size_t)orow * HD + col] = f2b(v);
                }
            }
    }
#pragma unroll
    for (int f = 0; f < 6; ++f) {
        s1v[f] += __shfl_xor(s1v[f], 16); s1v[f] += __shfl_xor(s1v[f], 32);
        s2v[f] += __shfl_xor(s2v[f], 16); s2v[f] += __shfl_xor(s2v[f], 32);
    }
    float* red = (float*)&bb[0][0];
    if (kg == 0) {
#pragma unroll
        for (int f = 0; f < 6; ++f) {
            const int col = cw * 96 + f * 16 + c;
            red[rw * 192 + col]       = s1v[f];
            red[384 + rw * 192 + col] = s2v[f];
        }
    }
    __syncthreads();
    if (tid < HD) {
        const float a1 = red[tid] + red[192 + tid];
        const float a2 = red[384 + tid] + red[576 + tid];
        atomicAdd((unsigned long long*)&statsq[tid],
                  (unsigned long long)(long long)llrintf(a1 * STAT_S));
        atomicAdd((unsigned long long*)&statsq[HD + tid],
                  (unsigned long long)(long long)llrintf(a2 * STAT_S));
    }
}

// ---------------- BN: scale/shift from fixed-point sum/sumsq ----------------
__global__ void stats_finalize(const long long* __restrict__ statsq,
    const float* __restrict__ gamma, const float* __restrict__ beta,
    float* __restrict__ scsh, int N)
{
    const int c = threadIdx.x;
    if (c >= HD) return;
    const float inv = 1.0f / (float)N;
    const float sum   = (float)statsq[c] * STAT_IS;
    const float sumsq = (float)statsq[HD + c] * STAT_IS;
    const float mu  = sum * inv;
    const float var = sumsq * inv - mu * mu;
    const float sc  = gamma[c] * rsqrtf(var + BNEPS);
    scsh[c]      = sc;
    scsh[HD + c] = beta[c] - mu * sc;
}

// ---------------- h = relu(hpre*scale + shift), bf16 in/out ----------------
__global__ __launch_bounds__(256) void norm_relu(const u16* __restrict__ hpre,
    u16* __restrict__ h, const float* __restrict__ scsh, int N)
{
    const int idx = blockIdx.x * 256 + threadIdx.x;   // 8-elem granule
    const int total = N * (HD / 8);
    if (idx >= total) return;
    const int c8 = idx % (HD / 8);
    const uint4 packed = ((const uint4*)hpre)[idx];
    const u16* pu = (const u16*)&packed;
    const float* sc = scsh + c8 * 8;
    const float* sh = scsh + HD + c8 * 8;
    u16 o[8];
#pragma unroll
    for (int j = 0; j < 8; ++j)
        o[j] = f2b(fmaxf(0.f, fmaf(b2f(pu[j]), sc[j], sh[j])));
    ((uint4*)h)[idx] = *(uint4*)o;
}

// ------- fused mean-pool (deterministic segment sum) + MLP head ----------
__global__ __launch_bounds__(192) void pool_head_kernel(
    const u16* __restrict__ h, const int* __restrict__ batch, int N,
    const float* __restrict__ w1, const float* __restrict__ b1,
    const float* __restrict__ w2, const float* __restrict__ b2,
    const float* __restrict__ ow, const float* __restrict__ ob,
    float* __restrict__ out)
{
    __shared__ float gv[HD];
    __shared__ float h1[HD];
    __shared__ float h2[HD];
    const int g = blockIdx.x;
    const int t = threadIdx.x;

    int lo = 0, hi = N;
    while (lo < hi) { int m = (lo + hi) >> 1; if (batch[m] < g) lo = m + 1; else hi = m; }
    const int start = lo;
    hi = N;
    while (lo < hi) { int m = (lo + hi) >> 1; if (batch[m] < g + 1) lo = m + 1; else hi = m; }
    const int end = lo;

    float s = 0.f;
    for (int r = start; r < end; ++r) s += b2f(h[(size_t)r * HD + t]);
    const float cnt = fmaxf((float)(end - start), 1.0f);
    gv[t] = s / cnt;
    __syncthreads();
    {
        float acc = b1[t];
        const float* wr = w1 + (size_t)t * HD;
#pragma unroll 4
        for (int k = 0; k < HD; ++k) acc = fmaf(gv[k], wr[k], acc);
        h1[t] = fmaxf(acc, 0.f);
    }
    __syncthreads();
    {
        float acc = b2[t];
        const float* wr = w2 + (size_t)t * HD;
#pragma unroll 4
        for (int k = 0; k < HD; ++k) acc = fmaf(h1[k], wr[k], acc);
        h2[t] = acc * ow[t];
    }
    __syncthreads();
    if (t == 0) {
        float acc = ob[0];
        for (int k = 0; k < HD; ++k) acc += h2[k];
        out[g] = acc;
    }
}

extern "C" void kernel_launch(void* const* d_in, const int* in_sizes, int n_in,
                              void* d_out, int out_size, void* d_ws, size_t ws_size,
                              hipStream_t stream)
{
    const float* x       = (const float*)d_in[0];
    const int*   ei      = (const int*)d_in[1];
    const int*   batch   = (const int*)d_in[2];
    const float* w_rel0  = (const float*)d_in[4];
    const float* b_rel0  = (const float*)d_in[5];
    const float* w_root0 = (const float*)d_in[6];
    const float* w_rel   = (const float*)d_in[7];
    const float* b_rel   = (const float*)d_in[8];
    const float* w_root  = (const float*)d_in[9];
    const float* bn_g    = (const float*)d_in[10];
    const float* bn_b    = (const float*)d_in[11];
    const float* hw1     = (const float*)d_in[12];
    const float* hb1     = (const float*)d_in[13];
    const float* hw2     = (const float*)d_in[14];
    const float* hb2     = (const float*)d_in[15];
    const float* ow      = (const float*)d_in[16];
    const float* ob      = (const float*)d_in[17];
    float* out = (float*)d_out;

    const int N = in_sizes[0] / FD0;
    const int E = in_sizes[1] / 2;
    const int* src = ei;
    const int* dst = ei + E;
    const int M = idiv(N, 256);   // psum entries (<=256 for N<=65536)

    char* ws = (char*)d_ws;
    size_t off = 0;
    u16* xb   = (u16*)(ws + off); off += (size_t)N * FD0 * 2;     // x bf16
    u16* hb   = (u16*)(ws + off); off += (size_t)N * HD * 2;      // h bf16
    u16* aggb = (u16*)(ws + off); off += (size_t)N * HD * 2;      // agg bf16
    u16* hpre = (u16*)(ws + off); off += (size_t)N * HD * 2;      // pre-BN bf16
    u16* wp0  = (u16*)(ws + off); off += (size_t)HD * 2 * FD0 * 2;    // layer0 weights
    u16* wp123= (u16*)(ws + off); off += (size_t)3 * HD * 2 * HD * 2; // layer1-3 weights
    off = (off + 15) & ~(size_t)15;
    long long* statsq = (long long*)(ws + off); off += 2 * HD * sizeof(long long);
    float*     scsh   = (float*)(ws + off);     off += 2 * HD * sizeof(float);
    int*       rowptr = (int*)(ws + off);       off += (size_t)(N + 1) * 4;
    int*       deg    = (int*)(ws + off);       off += (size_t)N * 4;
    int*       psum   = (int*)(ws + off);       off += (size_t)M * 4;
    int*       eidx   = (int*)(ws + off);       off += (size_t)E * 4;

    const dim3 b256(256), b192(192);

    // ---- conversions & CSR build (independent prep)
    convert_bf16<<<idiv(N * FD0 / 4, 256), b256, 0, stream>>>(x, xb, N * FD0 / 4);
    pack_weights<<<idiv(HD * 2 * FD0, 256), b256, 0, stream>>>(w_rel0, w_root0, wp0, FD0);
    for (int i = 0; i < 3; ++i)
        pack_weights<<<idiv(HD * 2 * HD, 256), b256, 0, stream>>>(
            w_rel + (size_t)i * HD * HD, w_root + (size_t)i * HD * HD,
            wp123 + (size_t)i * HD * 2 * HD, HD);
    hipMemsetAsync(deg, 0, (size_t)N * sizeof(int), stream);
    hist_kernel<<<idiv(E, 256), b256, 0, stream>>>(dst, deg, E);
    scan_partial<<<M, b256, 0, stream>>>(deg, psum, N);
    scan_small<<<1, b256, 0, stream>>>(psum, M);
    scan_expand<<<M, b256, 0, stream>>>(deg, psum, rowptr, N, E);
    hipMemsetAsync(deg, 0, (size_t)N * sizeof(int), stream);
    fill_kernel<<<idiv(E, 256), b256, 0, stream>>>(src, dst, rowptr, deg, eidx, E);

    // ---- layer 0 (K=128+128)
    hipMemsetAsync(statsq, 0, 2 * HD * sizeof(long long), stream);
    gather_kernel<FD0><<<idiv(N, 4), b256, 0, stream>>>(xb, rowptr, eidx, aggb, N);
    gemm_mfma<FD0, FD0><<<idiv(N, 64), b256, 0, stream>>>(aggb, xb, wp0, b_rel0,
                                                          hpre, statsq, N);
    stats_finalize<<<1, b192, 0, stream>>>(statsq, bn_g, bn_b, scsh, N);
    norm_relu<<<idiv(N * (HD / 8), 256), b256, 0, stream>>>(hpre, hb, scsh, N);

    // ---- layers 1..3 (K=192+192)
    for (int i = 0; i < 3; ++i) {
        hipMemsetAsync(statsq, 0, 2 * HD * sizeof(long long), stream);
        gather_kernel<HD><<<idiv(N, 4), b256, 0, stream>>>(hb, rowptr, eidx, aggb, N);
        gemm_mfma<HD, HD><<<idiv(N, 64), b256, 0, stream>>>(
            aggb, hb, wp123 + (size_t)i * HD * 2 * HD,
            b_rel + (size_t)i * HD, hpre, statsq, N);
        stats_finalize<<<1, b192, 0, stream>>>(statsq, bn_g + (size_t)(i + 1) * HD,
                                               bn_b + (size_t)(i + 1) * HD, scsh, N);
        norm_relu<<<idiv(N * (HD / 8), 256), b256, 0, stream>>>(hpre, hb, scsh, N);
    }

    // ---- fused global mean pool + head
    pool_head_kernel<<<NG, b192, 0, stream>>>(hb, batch, N, hw1, hb1, hw2, hb2,
                                              ow, ob, out);
}

// Round 9
// 492.357 us; speedup vs baseline: 3.0750x; 1.0575x over previous
//
#include <hip/hip_runtime.h>

#define HD 192
#define FD0 128
#define NG 256
#define BNEPS 1e-5f

#define AGG_S   2097152.0f        // 2^21 fixed-point scale for aggregation
#define AGG_IS  (1.0f / 2097152.0f)
#define STAT_S  1048576.0f        // 2^20 fixed-point scale for BN stats
#define STAT_IS (1.0f / 1048576.0f)

typedef unsigned short u16;
typedef __attribute__((ext_vector_type(8))) short bf16x8;
typedef __attribute__((ext_vector_type(4))) float f32x4;

static inline int idiv(int a, int b) { return (a + b - 1) / b; }

__device__ __forceinline__ float b2f(u16 u) {
    unsigned int v = ((unsigned int)u) << 16;
    return __builtin_bit_cast(float, v);
}
__device__ __forceinline__ u16 f2b(float f) {
    unsigned int x = __builtin_bit_cast(unsigned int, f);
    return (u16)((x + 0x7FFFu + ((x >> 16) & 1u)) >> 16);   // RNE
}

// async global->LDS, 16B per lane; LDS dest = uniform base + lane*16
__device__ __forceinline__ void async_cp16(const void* g, void* l) {
    __builtin_amdgcn_global_load_lds(
        (const __attribute__((address_space(1))) unsigned int*)g,
        (__attribute__((address_space(3))) unsigned int*)l, 16, 0, 0);
}

// ---------------- fp32 -> bf16 bulk convert ----------------
__global__ __launch_bounds__(256) void convert_bf16(const float* __restrict__ in,
                                                    u16* __restrict__ out, int n4)
{
    const int i = blockIdx.x * 256 + threadIdx.x;
    if (i >= n4) return;
    const float4 v = ((const float4*)in)[i];
    u16 o[4] = { f2b(v.x), f2b(v.y), f2b(v.z), f2b(v.w) };
    ((ushort4*)out)[i] = *(ushort4*)o;
}

// ------- pack [Wr | Wt] bf16 in MFMA-frag chunk order ------------------------
__global__ __launch_bounds__(256) void pack_weights(const float* __restrict__ wr,
    const float* __restrict__ wt, u16* __restrict__ out, int K)
{
    const int idx = blockIdx.x * 256 + threadIdx.x;
    const int total = HD * 2 * K;
    if (idx >= total) return;
    const int j  = idx & 7;
    const int t  = idx >> 3;
    const int c  = t & 15;
    const int kg = (t >> 4) & 3;
    const int rest = t >> 6;
    const int fglob = rest % 12;
    const int chunk = rest / 12;
    const int col = fglob * 16 + c;
    const int k   = chunk * 32 + kg * 8 + j;
    const float v = (k < K) ? wr[(size_t)col * K + k] : wt[(size_t)col * K + (k - K)];
    out[idx] = f2b(v);
}

// ------- transpose 192x192 fp32: wt[k][t] = w[t][k] (for coalesced head) ------
__global__ __launch_bounds__(256) void transpose_w(const float* __restrict__ w,
                                                   float* __restrict__ wt)
{
    const int idx = blockIdx.x * 256 + threadIdx.x;
    if (idx >= HD * HD) return;
    const int t = idx % HD, k = idx / HD;
    wt[idx] = w[(size_t)t * HD + k];
}

// ---------------- CSR build ----------------
__global__ __launch_bounds__(256) void hist_kernel(const int* __restrict__ dst,
                                                   int* __restrict__ deg, int E)
{
    const int e = blockIdx.x * 256 + threadIdx.x;
    if (e < E) atomicAdd(&deg[dst[e]], 1);
}

// hierarchical exclusive scan: partial sums -> scan sums -> expand
__global__ __launch_bounds__(256) void scan_partial(const int* __restrict__ deg,
                                                    int* __restrict__ psum, int N)
{
    __shared__ int s[256];
    const int t = threadIdx.x;
    const int i = blockIdx.x * 256 + t;
    s[t] = (i < N) ? deg[i] : 0;
    __syncthreads();
    for (int off = 128; off > 0; off >>= 1) {
        if (t < off) s[t] += s[t + off];
        __syncthreads();
    }
    if (t == 0) psum[blockIdx.x] = s[0];
}

__global__ __launch_bounds__(256) void scan_small(int* __restrict__ psum, int M)
{
    __shared__ int s[256];
    const int t = threadIdx.x;
    s[t] = (t < M) ? psum[t] : 0;
    __syncthreads();
    for (int off = 1; off < 256; off <<= 1) {
        const int u = (t >= off) ? s[t - off] : 0;
        __syncthreads();
        s[t] += u;
        __syncthreads();
    }
    if (t < M) psum[t] = (t == 0) ? 0 : s[t - 1];
}

__global__ __launch_bounds__(256) void scan_expand(const int* __restrict__ deg,
    const int* __restrict__ psum, int* __restrict__ rowptr, int N, int E)
{
    __shared__ int s[256];
    const int t = threadIdx.x;
    const int i = blockIdx.x * 256 + t;
    const int v = (i < N) ? deg[i] : 0;
    s[t] = v;
    __syncthreads();
    for (int off = 1; off < 256; off <<= 1) {
        const int u = (t >= off) ? s[t - off] : 0;
        __syncthreads();
        s[t] += u;
        __syncthreads();
    }
    if (i < N) rowptr[i] = psum[blockIdx.x] + s[t] - v;   // exclusive
    if (i == N - 1) rowptr[N] = E;
}

__global__ __launch_bounds__(256) void fill_kernel(const int* __restrict__ src,
    const int* __restrict__ dst, const int* __restrict__ rowptr,
    int* __restrict__ cursor, int* __restrict__ eidx, int E)
{
    const int e = blockIdx.x * 256 + threadIdx.x;
    if (e >= E) return;
    const int d = dst[e];
    const int p = atomicAdd(&cursor[d], 1);
    eidx[rowptr[d] + p] = src[e];
}

// ------- CSR gather: one WAVE per node; 2 edges/iter (half-wave each) -------
template<int FD>
__global__ __launch_bounds__(256) void gather_kernel(
    const u16* __restrict__ h, const int* __restrict__ rowptr,
    const int* __restrict__ eidx, u16* __restrict__ aggb, int N)
{
    constexpr int OCT = FD / 8;
    const int wave = threadIdx.x >> 6;
    const int lane = threadIdx.x & 63;
    const int half = lane >> 5;
    const int o    = lane & 31;
    const int n    = blockIdx.x * 4 + wave;
    if (n >= N) return;
    const int beg = rowptr[n], end = rowptr[n + 1];
    const bool active = (o < OCT);

    int acc[8];
#pragma unroll
    for (int i = 0; i < 8; ++i) acc[i] = 0;

    for (int j = beg + half; j < end; j += 2) {
        if (active) {
            const int s = eidx[j];
            const uint4 pv = *(const uint4*)(h + (size_t)s * FD + o * 8);
            const u16* pu = (const u16*)&pv;
#pragma unroll
            for (int i = 0; i < 8; ++i)
                acc[i] += __float2int_rn(b2f(pu[i]) * AGG_S);
        }
    }
#pragma unroll
    for (int i = 0; i < 8; ++i) acc[i] += __shfl_xor(acc[i], 32);

    if (half == 0 && active) {
        u16 ov[8];
#pragma unroll
        for (int i = 0; i < 8; ++i) ov[i] = f2b((float)acc[i] * AGG_IS);
        *(uint4*)(aggb + (size_t)n * FD + o * 8) = *(uint4*)ov;
    }
}

// -------- MFMA GEMM: Hpre = [A1|A2] @ Wb^T + bias ; BN sum/sumsq --------------
template<int K1, int K2>
__global__ __launch_bounds__(256, 3) void gemm_mfma(
    const u16* __restrict__ A1, const u16* __restrict__ A2,
    const u16* __restrict__ Wb, const float* __restrict__ bias,
    u16* __restrict__ Hout, long long* __restrict__ statsq, int N)
{
    constexpr int KC = K1 + K2;
    constexpr int NC = KC / 32;
    __shared__ u16 bb[2][6144];     // 2 x 12KB chunk buffers (also reused as red)

    const int tid  = threadIdx.x;
    const int wave = tid >> 6, lane = tid & 63;
    const int c    = lane & 15, kg = lane >> 4;
    const int rw   = wave >> 1, cw = wave & 1;
    const int row0 = blockIdx.x * 64;

    int arc[2];
#pragma unroll
    for (int m = 0; m < 2; ++m) {
        const int r = row0 + rw * 32 + m * 16 + c;
        arc[m] = r < N ? r : N - 1;
    }

    f32x4 acc[2][6];
#pragma unroll
    for (int m = 0; m < 2; ++m)
#pragma unroll
        for (int f = 0; f < 6; ++f) acc[m][f] = (f32x4){0.f, 0.f, 0.f, 0.f};

    auto stage = [&](int chunk, int buf) {
        const u16* g = Wb + (size_t)chunk * 6144 + wave * 1536 + lane * 8;
        u16* l = &bb[buf][wave * 1536];
#pragma unroll
        for (int i = 0; i < 3; ++i)
            async_cp16(g + i * 512, l + i * 512);
    };
    auto loadA = [&](int chunk, bf16x8* dst) {
        const int kk = chunk * 32;
#pragma unroll
        for (int m = 0; m < 2; ++m) {
            const u16* p = (kk < K1)
                ? A1 + (size_t)arc[m] * K1 + kk + kg * 8
                : A2 + (size_t)arc[m] * K2 + (kk - K1) + kg * 8;
            dst[m] = *(const bf16x8*)p;
        }
    };

    bf16x8 a_cur[2], a_nxt[2];
    stage(0, 0);
    loadA(0, a_cur);
    __syncthreads();

#pragma unroll
    for (int ch = 0; ch < NC; ++ch) {
        const int cb = ch & 1;
        if (ch + 1 < NC) {
            stage(ch + 1, cb ^ 1);
            loadA(ch + 1, a_nxt);
        }
#pragma unroll
        for (int f = 0; f < 6; ++f) {
            const int fglob = cw * 6 + f;
            const bf16x8 b = *(const bf16x8*)&bb[cb][(fglob * 64 + kg * 16 + c) * 8];
            acc[0][f] = __builtin_amdgcn_mfma_f32_16x16x32_bf16(a_cur[0], b, acc[0][f], 0, 0, 0);
            acc[1][f] = __builtin_amdgcn_mfma_f32_16x16x32_bf16(a_cur[1], b, acc[1][f], 0, 0, 0);
        }
        __syncthreads();
        a_cur[0] = a_nxt[0]; a_cur[1] = a_nxt[1];
    }

    // ---- epilogue: bias + store + BN partial sums ----
    float s1v[6], s2v[6];
#pragma unroll
    for (int f = 0; f < 6; ++f) { s1v[f] = 0.f; s2v[f] = 0.f; }

#pragma unroll
    for (int f = 0; f < 6; ++f) {
        const int col = cw * 96 + f * 16 + c;
        const float bv = bias[col];
#pragma unroll
        for (int m = 0; m < 2; ++m)
#pragma unroll
            for (int r = 0; r < 4; ++r) {
                const int orow = row0 + rw * 32 + m * 16 + kg * 4 + r;
                if (orow < N) {
                    const float v = acc[m][f][r] + bv;
                    s1v[f] += v;
                    s2v[f] += v * v;
                    Hout[(size_t)orow * HD + col] = f2b(v);
                }
            }
    }
#pragma unroll
    for (int f = 0; f < 6; ++f) {
        s1v[f] += __shfl_xor(s1v[f], 16); s1v[f] += __shfl_xor(s1v[f], 32);
        s2v[f] += __shfl_xor(s2v[f], 16); s2v[f] += __shfl_xor(s2v[f], 32);
    }
    float* red = (float*)&bb[0][0];
    if (kg == 0) {
#pragma unroll
        for (int f = 0; f < 6; ++f) {
            const int col = cw * 96 + f * 16 + c;
            red[rw * 192 + col]       = s1v[f];
            red[384 + rw * 192 + col] = s2v[f];
        }
    }
    __syncthreads();
    if (tid < HD) {
        const float a1 = red[tid] + red[192 + tid];
        const float a2 = red[384 + tid] + red[576 + tid];
        atomicAdd((unsigned long long*)&statsq[tid],
                  (unsigned long long)(long long)llrintf(a1 * STAT_S));
        atomicAdd((unsigned long long*)&statsq[HD + tid],
                  (unsigned long long)(long long)llrintf(a2 * STAT_S));
    }
}

// ---------------- BN: scale/shift from fixed-point sum/sumsq ----------------
__global__ void stats_finalize(const long long* __restrict__ statsq,
    const float* __restrict__ gamma, const float* __restrict__ beta,
    float* __restrict__ scsh, int N)
{
    const int c = threadIdx.x;
    if (c >= HD) return;
    const float inv = 1.0f / (float)N;
    const float sum   = (float)statsq[c] * STAT_IS;
    const float sumsq = (float)statsq[HD + c] * STAT_IS;
    const float mu  = sum * inv;
    const float var = sumsq * inv - mu * mu;
    const float sc  = gamma[c] * rsqrtf(var + BNEPS);
    scsh[c]      = sc;
    scsh[HD + c] = beta[c] - mu * sc;
}

// ---------------- h = relu(hpre*scale + shift), bf16 in/out ----------------
__global__ __launch_bounds__(256) void norm_relu(const u16* __restrict__ hpre,
    u16* __restrict__ h, const float* __restrict__ scsh, int N)
{
    const int idx = blockIdx.x * 256 + threadIdx.x;   // 8-elem granule
    const int total = N * (HD / 8);
    if (idx >= total) return;
    const int c8 = idx % (HD / 8);
    const uint4 packed = ((const uint4*)hpre)[idx];
    const u16* pu = (const u16*)&packed;
    const float* sc = scsh + c8 * 8;
    const float* sh = scsh + HD + c8 * 8;
    u16 o[8];
#pragma unroll
    for (int j = 0; j < 8; ++j)
        o[j] = f2b(fmaxf(0.f, fmaf(b2f(pu[j]), sc[j], sh[j])));
    ((uint4*)h)[idx] = *(uint4*)o;
}

// ------- fused mean-pool + MLP head, parallel rows + coalesced weights -------
// 256 thr: pooling as 8 row-parallel x 24 col-octets (16B loads);
// head dots read w1t/w2t in [k][t] layout -> coalesced; gv/h1 are LDS broadcasts.
__global__ __launch_bounds__(256) void pool_head_kernel(
    const u16* __restrict__ h, const int* __restrict__ batch, int N,
    const float* __restrict__ w1t, const float* __restrict__ b1,
    const float* __restrict__ w2t, const float* __restrict__ b2,
    const float* __restrict__ ow, const float* __restrict__ ob,
    float* __restrict__ out)
{
    __shared__ float pp[8][HD];
    __shared__ float gv[HD];
    __shared__ float h1[HD];
    __shared__ float h2[HD];
    const int g = blockIdx.x;
    const int t = threadIdx.x;
    const int rp = t >> 5;        // 0..7 row-parallel
    const int o  = t & 31;        // col octet, active < 24

    int lo = 0, hi = N;
    while (lo < hi) { int m = (lo + hi) >> 1; if (batch[m] < g) lo = m + 1; else hi = m; }
    const int start = lo;
    hi = N;
    while (lo < hi) { int m = (lo + hi) >> 1; if (batch[m] < g + 1) lo = m + 1; else hi = m; }
    const int end = lo;

    float facc[8];
#pragma unroll
    for (int i = 0; i < 8; ++i) facc[i] = 0.f;
    if (o < 24) {
        for (int r = start + rp; r < end; r += 8) {
            const uint4 pv = *(const uint4*)(h + (size_t)r * HD + o * 8);
            const u16* pu = (const u16*)&pv;
#pragma unroll
            for (int i = 0; i < 8; ++i) facc[i] += b2f(pu[i]);
        }
#pragma unroll
        for (int i = 0; i < 8; ++i) pp[rp][o * 8 + i] = facc[i];
    }
    __syncthreads();
    if (t < HD) {
        float s = 0.f;
#pragma unroll
        for (int r = 0; r < 8; ++r) s += pp[r][t];
        gv[t] = s / fmaxf((float)(end - start), 1.0f);
    }
    __syncthreads();
    if (t < HD) {
        float acc = b1[t];
#pragma unroll 4
        for (int k = 0; k < HD; ++k)
            acc = fmaf(gv[k], w1t[k * HD + t], acc);
        h1[t] = fmaxf(acc, 0.f);
    }
    __syncthreads();
    if (t < HD) {
        float acc = b2[t];
#pragma unroll 4
        for (int k = 0; k < HD; ++k)
            acc = fmaf(h1[k], w2t[k * HD + t], acc);
        h2[t] = acc * ow[t];
    }
    __syncthreads();
    if (t < 64) {
        float s = h2[t] + h2[t + 64] + h2[t + 128];
#pragma unroll
        for (int d = 1; d < 64; d <<= 1) s += __shfl_xor(s, d);
        if (t == 0) out[g] = s + ob[0];
    }
}

extern "C" void kernel_launch(void* const* d_in, const int* in_sizes, int n_in,
                              void* d_out, int out_size, void* d_ws, size_t ws_size,
                              hipStream_t stream)
{
    const float* x       = (const float*)d_in[0];
    const int*   ei      = (const int*)d_in[1];
    const int*   batch   = (const int*)d_in[2];
    const float* w_rel0  = (const float*)d_in[4];
    const float* b_rel0  = (const float*)d_in[5];
    const float* w_root0 = (const float*)d_in[6];
    const float* w_rel   = (const float*)d_in[7];
    const float* b_rel   = (const float*)d_in[8];
    const float* w_root  = (const float*)d_in[9];
    const float* bn_g    = (const float*)d_in[10];
    const float* bn_b    = (const float*)d_in[11];
    const float* hw1     = (const float*)d_in[12];
    const float* hb1     = (const float*)d_in[13];
    const float* hw2     = (const float*)d_in[14];
    const float* hb2     = (const float*)d_in[15];
    const float* ow      = (const float*)d_in[16];
    const float* ob      = (const float*)d_in[17];
    float* out = (float*)d_out;

    const int N = in_sizes[0] / FD0;
    const int E = in_sizes[1] / 2;
    const int* src = ei;
    const int* dst = ei + E;
    const int M = idiv(N, 256);   // psum entries (<=256 for N<=65536)

    char* ws = (char*)d_ws;
    size_t off = 0;
    u16* xb   = (u16*)(ws + off); off += (size_t)N * FD0 * 2;     // x bf16
    u16* hb   = (u16*)(ws + off); off += (size_t)N * HD * 2;      // h bf16
    u16* aggb = (u16*)(ws + off); off += (size_t)N * HD * 2;      // agg bf16
    u16* hpre = (u16*)(ws + off); off += (size_t)N * HD * 2;      // pre-BN bf16
    u16* wp0  = (u16*)(ws + off); off += (size_t)HD * 2 * FD0 * 2;    // layer0 weights
    u16* wp123= (u16*)(ws + off); off += (size_t)3 * HD * 2 * HD * 2; // layer1-3 weights
    off = (off + 15) & ~(size_t)15;
    float* w1t = (float*)(ws + off); off += (size_t)HD * HD * 4;  // head w1 transposed
    float* w2t = (float*)(ws + off); off += (size_t)HD * HD * 4;  // head w2 transposed
    long long* statsq = (long long*)(ws + off); off += 2 * HD * sizeof(long long);
    float*     scsh   = (float*)(ws + off);     off += 2 * HD * sizeof(float);
    int*       rowptr = (int*)(ws + off);       off += (size_t)(N + 1) * 4;
    int*       deg    = (int*)(ws + off);       off += (size_t)N * 4;
    int*       psum   = (int*)(ws + off);       off += (size_t)M * 4;
    int*       eidx   = (int*)(ws + off);       off += (size_t)E * 4;

    const dim3 b256(256), b192(192);

    // ---- conversions & CSR build (independent prep)
    convert_bf16<<<idiv(N * FD0 / 4, 256), b256, 0, stream>>>(x, xb, N * FD0 / 4);
    pack_weights<<<idiv(HD * 2 * FD0, 256), b256, 0, stream>>>(w_rel0, w_root0, wp0, FD0);
    for (int i = 0; i < 3; ++i)
        pack_weights<<<idiv(HD * 2 * HD, 256), b256, 0, stream>>>(
            w_rel + (size_t)i * HD * HD, w_root + (size_t)i * HD * HD,
            wp123 + (size_t)i * HD * 2 * HD, HD);
    transpose_w<<<idiv(HD * HD, 256), b256, 0, stream>>>(hw1, w1t);
    transpose_w<<<idiv(HD * HD, 256), b256, 0, stream>>>(hw2, w2t);
    hipMemsetAsync(deg, 0, (size_t)N * sizeof(int), stream);
    hist_kernel<<<idiv(E, 256), b256, 0, stream>>>(dst, deg, E);
    scan_partial<<<M, b256, 0, stream>>>(deg, psum, N);
    scan_small<<<1, b256, 0, stream>>>(psum, M);
    scan_expand<<<M, b256, 0, stream>>>(deg, psum, rowptr, N, E);
    hipMemsetAsync(deg, 0, (size_t)N * sizeof(int), stream);
    fill_kernel<<<idiv(E, 256), b256, 0, stream>>>(src, dst, rowptr, deg, eidx, E);

    // ---- layer 0 (K=128+128)
    hipMemsetAsync(statsq, 0, 2 * HD * sizeof(long long), stream);
    gather_kernel<FD0><<<idiv(N, 4), b256, 0, stream>>>(xb, rowptr, eidx, aggb, N);
    gemm_mfma<FD0, FD0><<<idiv(N, 64), b256, 0, stream>>>(aggb, xb, wp0, b_rel0,
                                                          hpre, statsq, N);
    stats_finalize<<<1, b192, 0, stream>>>(statsq, bn_g, bn_b, scsh, N);
    norm_relu<<<idiv(N * (HD / 8), 256), b256, 0, stream>>>(hpre, hb, scsh, N);

    // ---- layers 1..3 (K=192+192)
    for (int i = 0; i < 3; ++i) {
        hipMemsetAsync(statsq, 0, 2 * HD * sizeof(long long), stream);
        gather_kernel<HD><<<idiv(N, 4), b256, 0, stream>>>(hb, rowptr, eidx, aggb, N);
        gemm_mfma<HD, HD><<<idiv(N, 64), b256, 0, stream>>>(
            aggb, hb, wp123 + (size_t)i * HD * 2 * HD,
            b_rel + (size_t)i * HD, hpre, statsq, N);
        stats_finalize<<<1, b192, 0, stream>>>(statsq, bn_g + (size_t)(i + 1) * HD,
                                               bn_b + (size_t)(i + 1) * HD, scsh, N);
        norm_relu<<<idiv(N * (HD / 8), 256), b256, 0, stream>>>(hpre, hb, scsh, N);
    }

    // ---- fused global mean pool + head
    pool_head_kernel<<<NG, b256, 0, stream>>>(hb, batch, N, w1t, hb1, w2t, hb2,
                                              ow, ob, out);
}

// Round 10
// 455.176 us; speedup vs baseline: 3.3262x; 1.0817x over previous
//
#include <hip/hip_runtime.h>

#define HD 192
#define FD0 128
#define NG 256
#define BNEPS 1e-5f

#define STAT_S  1048576.0f        // 2^20 fixed-point scale for BN stats
#define STAT_IS (1.0f / 1048576.0f)
#define QS  2048.0f               // 2^11 fixed-point scale for i16 features
#define QIS (1.0f / 2048.0f)

typedef unsigned short u16;
typedef __attribute__((ext_vector_type(8))) short bf16x8;
typedef __attribute__((ext_vector_type(4))) float f32x4;

static inline int idiv(int a, int b) { return (a + b - 1) / b; }

__device__ __forceinline__ float b2f(u16 u) {
    unsigned int v = ((unsigned int)u) << 16;
    return __builtin_bit_cast(float, v);
}
__device__ __forceinline__ u16 f2b(float f) {
    unsigned int x = __builtin_bit_cast(unsigned int, f);
    return (u16)((x + 0x7FFFu + ((x >> 16) & 1u)) >> 16);   // RNE
}
__device__ __forceinline__ short f2q(float v) {
    return (short)__float2int_rn(fmaxf(fminf(v, 15.9f), -15.9f) * QS);
}

// async global->LDS, 16B per lane; LDS dest = uniform base + lane*16
__device__ __forceinline__ void async_cp16(const void* g, void* l) {
    __builtin_amdgcn_global_load_lds(
        (const __attribute__((address_space(1))) unsigned int*)g,
        (__attribute__((address_space(3))) unsigned int*)l, 16, 0, 0);
}

// ---------------- x fp32 -> bf16 + i16 (fused) ----------------
__global__ __launch_bounds__(256) void convert_x(const float* __restrict__ in,
    u16* __restrict__ xb, short* __restrict__ xq, int n4)
{
    const int i = blockIdx.x * 256 + threadIdx.x;
    if (i >= n4) return;
    const float4 v = ((const float4*)in)[i];
    u16 o[4] = { f2b(v.x), f2b(v.y), f2b(v.z), f2b(v.w) };
    ((ushort4*)xb)[i] = *(ushort4*)o;
    short q[4] = { f2q(v.x), f2q(v.y), f2q(v.z), f2q(v.w) };
    ((short4*)xq)[i] = *(short4*)q;
}

// ------- pack [Wr | Wt] bf16: [colhalf][chunk][f6][kg][c][j] -------
__global__ __launch_bounds__(256) void pack_weights(const float* __restrict__ wr,
    const float* __restrict__ wt, u16* __restrict__ out, int K)
{
    const int idx = blockIdx.x * 256 + threadIdx.x;
    const int total = HD * 2 * K;
    if (idx >= total) return;
    const int NCk = K / 16;            // chunks per colhalf (KC/32)
    const int j  = idx & 7;
    const int t  = idx >> 3;
    const int c  = t & 15;
    const int kg = (t >> 4) & 3;
    const int rest  = t >> 6;
    const int f6    = rest % 6;
    const int rest2 = rest / 6;
    const int chunk   = rest2 % NCk;
    const int colhalf = rest2 / NCk;
    const int col = colhalf * 96 + f6 * 16 + c;
    const int k   = chunk * 32 + kg * 8 + j;
    const float v = (k < K) ? wr[(size_t)col * K + k] : wt[(size_t)col * K + (k - K)];
    out[idx] = f2b(v);
}

// ------- transpose 192x192 fp32: wt[k][t] = w[t][k] (for coalesced head) ------
__global__ __launch_bounds__(256) void transpose_w(const float* __restrict__ w,
                                                   float* __restrict__ wt)
{
    const int idx = blockIdx.x * 256 + threadIdx.x;
    if (idx >= HD * HD) return;
    const int t = idx % HD, k = idx / HD;
    wt[idx] = w[(size_t)t * HD + k];
}

// ---------------- CSR build ----------------
__global__ __launch_bounds__(256) void hist_kernel(const int* __restrict__ dst,
                                                   int* __restrict__ deg, int E)
{
    const int e = blockIdx.x * 256 + threadIdx.x;
    if (e < E) atomicAdd(&deg[dst[e]], 1);
}

__global__ __launch_bounds__(256) void scan_partial(const int* __restrict__ deg,
                                                    int* __restrict__ psum, int N)
{
    __shared__ int s[256];
    const int t = threadIdx.x;
    const int i = blockIdx.x * 256 + t;
    s[t] = (i < N) ? deg[i] : 0;
    __syncthreads();
    for (int off = 128; off > 0; off >>= 1) {
        if (t < off) s[t] += s[t + off];
        __syncthreads();
    }
    if (t == 0) psum[blockIdx.x] = s[0];
}

__global__ __launch_bounds__(256) void scan_small(int* __restrict__ psum, int M)
{
    __shared__ int s[256];
    const int t = threadIdx.x;
    s[t] = (t < M) ? psum[t] : 0;
    __syncthreads();
    for (int off = 1; off < 256; off <<= 1) {
        const int u = (t >= off) ? s[t - off] : 0;
        __syncthreads();
        s[t] += u;
        __syncthreads();
    }
    if (t < M) psum[t] = (t == 0) ? 0 : s[t - 1];
}

__global__ __launch_bounds__(256) void scan_expand(const int* __restrict__ deg,
    const int* __restrict__ psum, int* __restrict__ rowptr, int N, int E)
{
    __shared__ int s[256];
    const int t = threadIdx.x;
    const int i = blockIdx.x * 256 + t;
    const int v = (i < N) ? deg[i] : 0;
    s[t] = v;
    __syncthreads();
    for (int off = 1; off < 256; off <<= 1) {
        const int u = (t >= off) ? s[t - off] : 0;
        __syncthreads();
        s[t] += u;
        __syncthreads();
    }
    if (i < N) rowptr[i] = psum[blockIdx.x] + s[t] - v;   // exclusive
    if (i == N - 1) rowptr[N] = E;
}

__global__ __launch_bounds__(256) void fill_kernel(const int* __restrict__ src,
    const int* __restrict__ dst, const int* __restrict__ rowptr,
    int* __restrict__ cursor, int* __restrict__ eidx, int E)
{
    const int e = blockIdx.x * 256 + threadIdx.x;
    if (e >= E) return;
    const int d = dst[e];
    const int p = atomicAdd(&cursor[d], 1);
    eidx[rowptr[d] + p] = src[e];
}

// ------- CSR gather from i16 features: full 64-lane, int accumulation -------
// wave per node; lane = (half, colgroup): 32 groups x GW cols; 2 edges in flight.
template<int FD>
__global__ __launch_bounds__(256) void gather_kernel(
    const short* __restrict__ hq, const int* __restrict__ rowptr,
    const int* __restrict__ eidx, u16* __restrict__ aggb, int N)
{
    constexpr int GW = FD / 32;           // cols per lane: 6 (192) or 4 (128)
    constexpr int ND = GW / 2;            // dwords per load
    const int lane = threadIdx.x & 63;
    const int half = lane >> 5;
    const int g    = lane & 31;
    const int n    = blockIdx.x * 4 + (threadIdx.x >> 6);
    if (n >= N) return;
    const int beg = rowptr[n], end = rowptr[n + 1];

    int acc[GW];
#pragma unroll
    for (int i = 0; i < GW; ++i) acc[i] = 0;

    int j = beg + half;
    for (; j + 2 < end; j += 4) {         // 2 edges in flight per lane
        const int s0 = eidx[j], s1 = eidx[j + 2];
        const unsigned int* p0 = (const unsigned int*)(hq + (size_t)s0 * FD + g * GW);
        const unsigned int* p1 = (const unsigned int*)(hq + (size_t)s1 * FD + g * GW);
        unsigned int u0[ND], u1[ND];
#pragma unroll
        for (int d = 0; d < ND; ++d) { u0[d] = p0[d]; u1[d] = p1[d]; }
#pragma unroll
        for (int d = 0; d < ND; ++d) {
            acc[2*d]   += (int)(short)(u0[d] & 0xffffu) + (int)(short)(u1[d] & 0xffffu);
            acc[2*d+1] += (((int)u0[d]) >> 16) + (((int)u1[d]) >> 16);
        }
    }
    if (j < end) {
        const int s0 = eidx[j];
        const unsigned int* p0 = (const unsigned int*)(hq + (size_t)s0 * FD + g * GW);
#pragma unroll
        for (int d = 0; d < ND; ++d) {
            const unsigned int u = p0[d];
            acc[2*d]   += (int)(short)(u & 0xffffu);
            acc[2*d+1] += ((int)u) >> 16;
        }
    }
#pragma unroll
    for (int i = 0; i < GW; ++i) acc[i] += __shfl_xor(acc[i], 32);

    if (half == 0) {
        unsigned int* q = (unsigned int*)(aggb + (size_t)n * FD + g * GW);
#pragma unroll
        for (int d = 0; d < ND; ++d) {
            const u16 lo = f2b((float)acc[2*d]   * QIS);
            const u16 hi = f2b((float)acc[2*d+1] * QIS);
            q[d] = (unsigned int)lo | ((unsigned int)hi << 16);
        }
    }
}

// -------- MFMA GEMM, barrier-free K-loop: Hpre = [A1|A2] @ Wb^T + bias --------
// block = 192 rows x 96 cols (colhalf from blockIdx); 4 waves x 48 rows.
// Whole B-half panel (96 x KC) resident in LDS; staged once via global_load_lds.
template<int K1, int K2>
__global__ __launch_bounds__(256, 2) void gemm_mfma(
    const u16* __restrict__ A1, const u16* __restrict__ A2,
    const u16* __restrict__ Wb, const float* __restrict__ bias,
    u16* __restrict__ Hout, long long* __restrict__ statsq, int N)
{
    constexpr int KC  = K1 + K2;
    constexpr int NC  = KC / 32;
    constexpr int NC1 = K1 / 32;
    __shared__ u16 bsh[96 * KC];          // 73.7KB (KC=384) / 49.2KB (KC=256)

    const int tid  = threadIdx.x;
    const int wave = tid >> 6, lane = tid & 63;
    const int c = lane & 15, kg = lane >> 4;
    const int colhalf = blockIdx.x & 1;
    const int row0 = (blockIdx.x >> 1) * 192 + wave * 48;

    {   // stage whole B-half panel linearly
        const u16* wsrc = Wb + (size_t)colhalf * 96 * KC + tid * 8;
        u16* ldst = bsh + tid * 8;
        constexpr int NST = (96 * KC) / (256 * 8);
#pragma unroll
        for (int i = 0; i < NST; ++i)
            async_cp16(wsrc + i * 2048, ldst + i * 2048);
    }

    int arc[3];
#pragma unroll
    for (int m = 0; m < 3; ++m) {
        const int r = row0 + m * 16 + c;
        arc[m] = r < N ? r : N - 1;
    }

    f32x4 acc[3][6];
#pragma unroll
    for (int m = 0; m < 3; ++m)
#pragma unroll
        for (int f = 0; f < 6; ++f) acc[m][f] = (f32x4){0.f, 0.f, 0.f, 0.f};

    __syncthreads();   // drains global_load_lds (vmcnt) + all waves ready

#pragma unroll 2
    for (int ch = 0; ch < NC; ++ch) {
        const int kk = ch * 32;
        bf16x8 a[3];
#pragma unroll
        for (int m = 0; m < 3; ++m) {
            const u16* p = (ch < NC1) ? (A1 + (size_t)arc[m] * K1 + kk + kg * 8)
                                      : (A2 + (size_t)arc[m] * K2 + (kk - K1) + kg * 8);
            a[m] = *(const bf16x8*)p;
        }
#pragma unroll
        for (int f = 0; f < 6; ++f) {
            const bf16x8 b = *(const bf16x8*)&bsh[ch * 3072 + f * 512 + kg * 128 + c * 8];
#pragma unroll
            for (int m = 0; m < 3; ++m)
                acc[m][f] = __builtin_amdgcn_mfma_f32_16x16x32_bf16(a[m], b, acc[m][f], 0, 0, 0);
        }
    }

    // ---- epilogue: bias + store + BN partial sums ----
    float s1v[6], s2v[6];
#pragma unroll
    for (int f = 0; f < 6; ++f) { s1v[f] = 0.f; s2v[f] = 0.f; }

#pragma unroll
    for (int f = 0; f < 6; ++f) {
        const int col = colhalf * 96 + f * 16 + c;
        const float bv = bias[col];
#pragma unroll
        for (int m = 0; m < 3; ++m)
#pragma unroll
            for (int r = 0; r < 4; ++r) {
                const int orow = row0 + m * 16 + kg * 4 + r;
                if (orow < N) {
                    const float v = acc[m][f][r] + bv;
                    s1v[f] += v;
                    s2v[f] += v * v;
                    Hout[(size_t)orow * HD + col] = f2b(v);
                }
            }
    }
#pragma unroll
    for (int f = 0; f < 6; ++f) {
        s1v[f] += __shfl_xor(s1v[f], 16); s1v[f] += __shfl_xor(s1v[f], 32);
        s2v[f] += __shfl_xor(s2v[f], 16); s2v[f] += __shfl_xor(s2v[f], 32);
    }
    __syncthreads();                       // all waves done reading bsh
    float* red = (float*)bsh;              // reuse panel LDS: 768 floats
    if (kg == 0) {
#pragma unroll
        for (int f = 0; f < 6; ++f) {
            red[wave * 96 + f * 16 + c]       = s1v[f];
            red[384 + wave * 96 + f * 16 + c] = s2v[f];
        }
    }
    __syncthreads();
    if (tid < 96) {
        float a1 = 0.f, a2 = 0.f;
#pragma unroll
        for (int w = 0; w < 4; ++w) { a1 += red[w * 96 + tid]; a2 += red[384 + w * 96 + tid]; }
        const int col = colhalf * 96 + tid;
        atomicAdd((unsigned long long*)&statsq[col],
                  (unsigned long long)(long long)llrintf(a1 * STAT_S));
        atomicAdd((unsigned long long*)&statsq[HD + col],
                  (unsigned long long)(long long)llrintf(a2 * STAT_S));
    }
}

// ------- h = relu(hpre*scale + shift) -> bf16 + i16; BN params from statsq -----
__global__ __launch_bounds__(256) void norm_relu(const u16* __restrict__ hpre,
    u16* __restrict__ hb, short* __restrict__ hq,
    const long long* __restrict__ statsq,
    const float* __restrict__ gamma, const float* __restrict__ beta, int N)
{
    __shared__ float sc[HD], sh[HD];
    const int t = threadIdx.x;
    if (t < HD) {
        const float inv = 1.0f / (float)N;
        const float sum = (float)statsq[t] * STAT_IS;
        const float sq  = (float)statsq[HD + t] * STAT_IS;
        const float mu  = sum * inv;
        const float var = sq * inv - mu * mu;
        const float s   = gamma[t] * rsqrtf(var + BNEPS);
        sc[t] = s; sh[t] = beta[t] - mu * s;
    }
    __syncthreads();
    const int idx = blockIdx.x * 256 + t;
    const int total = N * (HD / 8);
    if (idx >= total) return;
    const int c8 = idx % (HD / 8);
    uint4 packed = ((const uint4*)hpre)[idx];
    const u16* pu = (const u16*)&packed;
    u16 ob[8]; short oq[8];
#pragma unroll
    for (int j = 0; j < 8; ++j) {
        const int cc = c8 * 8 + j;
        const float v = fmaxf(0.f, fmaf(b2f(pu[j]), sc[cc], sh[cc]));
        ob[j] = f2b(v);
        oq[j] = (short)__float2int_rn(fminf(v, 15.9f) * QS);
    }
    ((uint4*)hb)[idx] = *(uint4*)ob;
    ((uint4*)hq)[idx] = *(uint4*)oq;
}

// ------- fused mean-pool + MLP head, parallel rows + coalesced weights -------
__global__ __launch_bounds__(256) void pool_head_kernel(
    const u16* __restrict__ h, const int* __restrict__ batch, int N,
    const float* __restrict__ w1t, const float* __restrict__ b1,
    const float* __restrict__ w2t, const float* __restrict__ b2,
    const float* __restrict__ ow, const float* __restrict__ ob,
    float* __restrict__ out)
{
    __shared__ float pp[8][HD];
    __shared__ float gv[HD];
    __shared__ float h1[HD];
    __shared__ float h2[HD];
    const int g = blockIdx.x;
    const int t = threadIdx.x;
    const int rp = t >> 5;
    const int o  = t & 31;

    int lo = 0, hi = N;
    while (lo < hi) { int m = (lo + hi) >> 1; if (batch[m] < g) lo = m + 1; else hi = m; }
    const int start = lo;
    hi = N;
    while (lo < hi) { int m = (lo + hi) >> 1; if (batch[m] < g + 1) lo = m + 1; else hi = m; }
    const int end = lo;

    float facc[8];
#pragma unroll
    for (int i = 0; i < 8; ++i) facc[i] = 0.f;
    if (o < 24) {
        for (int r = start + rp; r < end; r += 8) {
            const uint4 pv = *(const uint4*)(h + (size_t)r * HD + o * 8);
            const u16* pu = (const u16*)&pv;
#pragma unroll
            for (int i = 0; i < 8; ++i) facc[i] += b2f(pu[i]);
        }
#pragma unroll
        for (int i = 0; i < 8; ++i) pp[rp][o * 8 + i] = facc[i];
    }
    __syncthreads();
    if (t < HD) {
        float s = 0.f;
#pragma unroll
        for (int r = 0; r < 8; ++r) s += pp[r][t];
        gv[t] = s / fmaxf((float)(end - start), 1.0f);
    }
    __syncthreads();
    if (t < HD) {
        float acc = b1[t];
#pragma unroll 4
        for (int k = 0; k < HD; ++k)
            acc = fmaf(gv[k], w1t[k * HD + t], acc);
        h1[t] = fmaxf(acc, 0.f);
    }
    __syncthreads();
    if (t < HD) {
        float acc = b2[t];
#pragma unroll 4
        for (int k = 0; k < HD; ++k)
            acc = fmaf(h1[k], w2t[k * HD + t], acc);
        h2[t] = acc * ow[t];
    }
    __syncthreads();
    if (t < 64) {
        float s = h2[t] + h2[t + 64] + h2[t + 128];
#pragma unroll
        for (int d = 1; d < 64; d <<= 1) s += __shfl_xor(s, d);
        if (t == 0) out[g] = s + ob[0];
    }
}

extern "C" void kernel_launch(void* const* d_in, const int* in_sizes, int n_in,
                              void* d_out, int out_size, void* d_ws, size_t ws_size,
                              hipStream_t stream)
{
    const float* x       = (const float*)d_in[0];
    const int*   ei      = (const int*)d_in[1];
    const int*   batch   = (const int*)d_in[2];
    const float* w_rel0  = (const float*)d_in[4];
    const float* b_rel0  = (const float*)d_in[5];
    const float* w_root0 = (const float*)d_in[6];
    const float* w_rel   = (const float*)d_in[7];
    const float* b_rel   = (const float*)d_in[8];
    const float* w_root  = (const float*)d_in[9];
    const float* bn_g    = (const float*)d_in[10];
    const float* bn_b    = (const float*)d_in[11];
    const float* hw1     = (const float*)d_in[12];
    const float* hb1     = (const float*)d_in[13];
    const float* hw2     = (const float*)d_in[14];
    const float* hb2     = (const float*)d_in[15];
    const float* ow      = (const float*)d_in[16];
    const float* ob      = (const float*)d_in[17];
    float* out = (float*)d_out;

    const int N = in_sizes[0] / FD0;
    const int E = in_sizes[1] / 2;
    const int* src = ei;
    const int* dst = ei + E;
    const int M = idiv(N, 256);

    char* ws = (char*)d_ws;
    size_t off = 0;
    u16*   xb   = (u16*)(ws + off);   off += (size_t)N * FD0 * 2;
    short* xq   = (short*)(ws + off); off += (size_t)N * FD0 * 2;
    u16*   hb   = (u16*)(ws + off);   off += (size_t)N * HD * 2;
    short* hq   = (short*)(ws + off); off += (size_t)N * HD * 2;
    u16*   aggb = (u16*)(ws + off);   off += (size_t)N * HD * 2;
    u16*   hpre = (u16*)(ws + off);   off += (size_t)N * HD * 2;
    u16*   wp0  = (u16*)(ws + off);   off += (size_t)HD * 2 * FD0 * 2;
    u16*   wp123= (u16*)(ws + off);   off += (size_t)3 * HD * 2 * HD * 2;
    off = (off + 15) & ~(size_t)15;
    float* w1t = (float*)(ws + off); off += (size_t)HD * HD * 4;
    float* w2t = (float*)(ws + off); off += (size_t)HD * HD * 4;
    long long* statsq = (long long*)(ws + off); off += 2 * HD * sizeof(long long);
    int*   rowptr = (int*)(ws + off); off += (size_t)(N + 1) * 4;
    int*   deg    = (int*)(ws + off); off += (size_t)N * 4;
    int*   psum   = (int*)(ws + off); off += (size_t)M * 4;
    int*   eidx   = (int*)(ws + off); off += (size_t)E * 4;

    const dim3 b256(256);

    // ---- conversions & CSR build
    convert_x<<<idiv(N * FD0 / 4, 256), b256, 0, stream>>>(x, xb, xq, N * FD0 / 4);
    pack_weights<<<idiv(HD * 2 * FD0, 256), b256, 0, stream>>>(w_rel0, w_root0, wp0, FD0);
    for (int i = 0; i < 3; ++i)
        pack_weights<<<idiv(HD * 2 * HD, 256), b256, 0, stream>>>(
            w_rel + (size_t)i * HD * HD, w_root + (size_t)i * HD * HD,
            wp123 + (size_t)i * HD * 2 * HD, HD);
    transpose_w<<<idiv(HD * HD, 256), b256, 0, stream>>>(hw1, w1t);
    transpose_w<<<idiv(HD * HD, 256), b256, 0, stream>>>(hw2, w2t);
    hipMemsetAsync(deg, 0, (size_t)N * sizeof(int), stream);
    hist_kernel<<<idiv(E, 256), b256, 0, stream>>>(dst, deg, E);
    scan_partial<<<M, b256, 0, stream>>>(deg, psum, N);
    scan_small<<<1, b256, 0, stream>>>(psum, M);
    scan_expand<<<M, b256, 0, stream>>>(deg, psum, rowptr, N, E);
    hipMemsetAsync(deg, 0, (size_t)N * sizeof(int), stream);
    fill_kernel<<<idiv(E, 256), b256, 0, stream>>>(src, dst, rowptr, deg, eidx, E);

    // ---- layer 0 (K=128+128)
    hipMemsetAsync(statsq, 0, 2 * HD * sizeof(long long), stream);
    gather_kernel<FD0><<<idiv(N, 4), b256, 0, stream>>>(xq, rowptr, eidx, aggb, N);
    gemm_mfma<FD0, FD0><<<idiv(N, 192) * 2, b256, 0, stream>>>(aggb, xb, wp0, b_rel0,
                                                               hpre, statsq, N);
    norm_relu<<<idiv(N * (HD / 8), 256), b256, 0, stream>>>(hpre, hb, hq, statsq,
                                                            bn_g, bn_b, N);

    // ---- layers 1..3 (K=192+192)
    for (int i = 0; i < 3; ++i) {
        hipMemsetAsync(statsq, 0, 2 * HD * sizeof(long long), stream);
        gather_kernel<HD><<<idiv(N, 4), b256, 0, stream>>>(hq, rowptr, eidx, aggb, N);
        gemm_mfma<HD, HD><<<idiv(N, 192) * 2, b256, 0, stream>>>(
            aggb, hb, wp123 + (size_t)i * HD * 2 * HD,
            b_rel + (size_t)i * HD, hpre, statsq, N);
        norm_relu<<<idiv(N * (HD / 8), 256), b256, 0, stream>>>(hpre, hb, hq, statsq,
            bn_g + (size_t)(i + 1) * HD, bn_b + (size_t)(i + 1) * HD, N);
    }

    // ---- fused global mean pool + head
    pool_head_kernel<<<NG, b256, 0, stream>>>(hb, batch, N, w1t, hb1, w2t, hb2,
                                              ow, ob, out);
}

// Round 11
// 405.448 us; speedup vs baseline: 3.7342x; 1.1227x over previous
//
#include <hip/hip_runtime.h>

#define HD 192
#define FD0 128
#define NG 256
#define BNEPS 1e-5f

#define STAT_S  1048576.0f        // 2^20 fixed-point scale for BN stats
#define STAT_IS (1.0f / 1048576.0f)
#define QS  2048.0f               // 2^11 fixed-point scale for i16 features
#define QIS (1.0f / 2048.0f)

typedef unsigned short u16;
typedef __attribute__((ext_vector_type(8))) short bf16x8;
typedef __attribute__((ext_vector_type(4))) float f32x4;

static inline int idiv(int a, int b) { return (a + b - 1) / b; }

__device__ __forceinline__ float b2f(u16 u) {
    unsigned int v = ((unsigned int)u) << 16;
    return __builtin_bit_cast(float, v);
}
__device__ __forceinline__ u16 f2b(float f) {
    unsigned int x = __builtin_bit_cast(unsigned int, f);
    return (u16)((x + 0x7FFFu + ((x >> 16) & 1u)) >> 16);   // RNE
}
__device__ __forceinline__ short f2q(float v) {
    return (short)__float2int_rn(fmaxf(fminf(v, 15.9f), -15.9f) * QS);
}

// async global->LDS, 16B per lane; LDS dest = uniform base + lane*16
__device__ __forceinline__ void async_cp16(const void* g, void* l) {
    __builtin_amdgcn_global_load_lds(
        (const __attribute__((address_space(1))) unsigned int*)g,
        (__attribute__((address_space(3))) unsigned int*)l, 16, 0, 0);
}

// ---------------- x fp32 -> bf16 + i16 (fused) ----------------
__global__ __launch_bounds__(256) void convert_x(const float* __restrict__ in,
    u16* __restrict__ xb, short* __restrict__ xq, int n4)
{
    const int i = blockIdx.x * 256 + threadIdx.x;
    if (i >= n4) return;
    const float4 v = ((const float4*)in)[i];
    u16 o[4] = { f2b(v.x), f2b(v.y), f2b(v.z), f2b(v.w) };
    ((ushort4*)xb)[i] = *(ushort4*)o;
    short q[4] = { f2q(v.x), f2q(v.y), f2q(v.z), f2q(v.w) };
    ((short4*)xq)[i] = *(short4*)q;
}

// ------- pack [Wr | Wt] bf16 in MFMA-frag chunk order: [chunk][f12][kg][c][j] --
__global__ __launch_bounds__(256) void pack_weights(const float* __restrict__ wr,
    const float* __restrict__ wt, u16* __restrict__ out, int K)
{
    const int idx = blockIdx.x * 256 + threadIdx.x;
    const int total = HD * 2 * K;
    if (idx >= total) return;
    const int j  = idx & 7;
    const int t  = idx >> 3;
    const int c  = t & 15;
    const int kg = (t >> 4) & 3;
    const int rest = t >> 6;
    const int fglob = rest % 12;
    const int chunk = rest / 12;
    const int col = fglob * 16 + c;
    const int k   = chunk * 32 + kg * 8 + j;
    const float v = (k < K) ? wr[(size_t)col * K + k] : wt[(size_t)col * K + (k - K)];
    out[idx] = f2b(v);
}

// ------- transpose 192x192 fp32: wt[k][t] = w[t][k] (for coalesced head) ------
__global__ __launch_bounds__(256) void transpose_w(const float* __restrict__ w,
                                                   float* __restrict__ wt)
{
    const int idx = blockIdx.x * 256 + threadIdx.x;
    if (idx >= HD * HD) return;
    const int t = idx % HD, k = idx / HD;
    wt[idx] = w[(size_t)t * HD + k];
}

// ---------------- CSR build ----------------
__global__ __launch_bounds__(256) void hist_kernel(const int* __restrict__ dst,
                                                   int* __restrict__ deg, int E)
{
    const int e = blockIdx.x * 256 + threadIdx.x;
    if (e < E) atomicAdd(&deg[dst[e]], 1);
}

__global__ __launch_bounds__(256) void scan_partial(const int* __restrict__ deg,
                                                    int* __restrict__ psum, int N)
{
    __shared__ int s[256];
    const int t = threadIdx.x;
    const int i = blockIdx.x * 256 + t;
    s[t] = (i < N) ? deg[i] : 0;
    __syncthreads();
    for (int off = 128; off > 0; off >>= 1) {
        if (t < off) s[t] += s[t + off];
        __syncthreads();
    }
    if (t == 0) psum[blockIdx.x] = s[0];
}

__global__ __launch_bounds__(256) void scan_small(int* __restrict__ psum, int M)
{
    __shared__ int s[256];
    const int t = threadIdx.x;
    s[t] = (t < M) ? psum[t] : 0;
    __syncthreads();
    for (int off = 1; off < 256; off <<= 1) {
        const int u = (t >= off) ? s[t - off] : 0;
        __syncthreads();
        s[t] += u;
        __syncthreads();
    }
    if (t < M) psum[t] = (t == 0) ? 0 : s[t - 1];
}

__global__ __launch_bounds__(256) void scan_expand(const int* __restrict__ deg,
    const int* __restrict__ psum, int* __restrict__ rowptr, int N, int E)
{
    __shared__ int s[256];
    const int t = threadIdx.x;
    const int i = blockIdx.x * 256 + t;
    const int v = (i < N) ? deg[i] : 0;
    s[t] = v;
    __syncthreads();
    for (int off = 1; off < 256; off <<= 1) {
        const int u = (t >= off) ? s[t - off] : 0;
        __syncthreads();
        s[t] += u;
        __syncthreads();
    }
    if (i < N) rowptr[i] = psum[blockIdx.x] + s[t] - v;   // exclusive
    if (i == N - 1) rowptr[N] = E;
}

__global__ __launch_bounds__(256) void fill_kernel(const int* __restrict__ src,
    const int* __restrict__ dst, const int* __restrict__ rowptr,
    int* __restrict__ cursor, int* __restrict__ eidx, int E)
{
    const int e = blockIdx.x * 256 + threadIdx.x;
    if (e >= E) return;
    const int d = dst[e];
    const int p = atomicAdd(&cursor[d], 1);
    eidx[rowptr[d] + p] = src[e];
}

// ------- CSR gather from i16 features: full 64-lane, 4-edge ILP -------
template<int FD>
__global__ __launch_bounds__(256) void gather_kernel(
    const short* __restrict__ hq, const int* __restrict__ rowptr,
    const int* __restrict__ eidx, u16* __restrict__ aggb, int N)
{
    constexpr int GW = FD / 32;           // cols per lane: 6 (192) or 4 (128)
    constexpr int ND = GW / 2;            // dwords per load
    const int lane = threadIdx.x & 63;
    const int half = lane >> 5;
    const int g    = lane & 31;
    const int n    = blockIdx.x * 4 + (threadIdx.x >> 6);
    if (n >= N) return;
    const int beg = rowptr[n], end = rowptr[n + 1];

    int acc[GW];
#pragma unroll
    for (int i = 0; i < GW; ++i) acc[i] = 0;

    int j = beg + half;
    for (; j + 6 < end; j += 8) {         // 4 edges in flight per lane
        const int s0 = eidx[j],     s1 = eidx[j + 2];
        const int s2 = eidx[j + 4], s3 = eidx[j + 6];
        const unsigned int* p0 = (const unsigned int*)(hq + (size_t)s0 * FD + g * GW);
        const unsigned int* p1 = (const unsigned int*)(hq + (size_t)s1 * FD + g * GW);
        const unsigned int* p2 = (const unsigned int*)(hq + (size_t)s2 * FD + g * GW);
        const unsigned int* p3 = (const unsigned int*)(hq + (size_t)s3 * FD + g * GW);
        unsigned int u0[ND], u1[ND], u2[ND], u3[ND];
#pragma unroll
        for (int d = 0; d < ND; ++d) { u0[d] = p0[d]; u1[d] = p1[d]; u2[d] = p2[d]; u3[d] = p3[d]; }
#pragma unroll
        for (int d = 0; d < ND; ++d) {
            acc[2*d]   += (int)(short)(u0[d] & 0xffffu) + (int)(short)(u1[d] & 0xffffu)
                        + (int)(short)(u2[d] & 0xffffu) + (int)(short)(u3[d] & 0xffffu);
            acc[2*d+1] += (((int)u0[d]) >> 16) + (((int)u1[d]) >> 16)
                        + (((int)u2[d]) >> 16) + (((int)u3[d]) >> 16);
        }
    }
    for (; j < end; j += 2) {
        const int s0 = eidx[j];
        const unsigned int* p0 = (const unsigned int*)(hq + (size_t)s0 * FD + g * GW);
#pragma unroll
        for (int d = 0; d < ND; ++d) {
            const unsigned int u = p0[d];
            acc[2*d]   += (int)(short)(u & 0xffffu);
            acc[2*d+1] += ((int)u) >> 16;
        }
    }
#pragma unroll
    for (int i = 0; i < GW; ++i) acc[i] += __shfl_xor(acc[i], 32);

    if (half == 0) {
        unsigned int* q = (unsigned int*)(aggb + (size_t)n * FD + g * GW);
#pragma unroll
        for (int d = 0; d < ND; ++d) {
            const u16 lo = f2b((float)acc[2*d]   * QIS);
            const u16 hi = f2b((float)acc[2*d+1] * QIS);
            q[d] = (unsigned int)lo | ((unsigned int)hi << 16);
        }
    }
}

// -------- MFMA GEMM: 512 thr / 8 waves; block = 256 rows x 192 cols ----------
// Full B panel (192 x KC) resident in LDS, staged once; barrier-free K-loop.
// wave = 32 rows: each B ds_read feeds 2 MFMAs; A loads independent (no fences).
template<int K1, int K2>
__global__ __launch_bounds__(512, 1) void gemm_mfma(
    const u16* __restrict__ A1, const u16* __restrict__ A2,
    const u16* __restrict__ Wb, const float* __restrict__ bias,
    u16* __restrict__ Hout, long long* __restrict__ statsq, int N)
{
    constexpr int KC  = K1 + K2;
    constexpr int NC  = KC / 32;
    constexpr int NC1 = K1 / 32;
    __shared__ u16 bsh[HD * KC];          // 98KB (KC=256) / 147KB (KC=384)

    const int tid  = threadIdx.x;
    const int wave = tid >> 6, lane = tid & 63;
    const int c = lane & 15, kg = lane >> 4;
    const int row0 = blockIdx.x * 256 + wave * 32;

    {   // stage whole panel linearly (512 thr x 16B = 8KB per iter)
        constexpr int NST = (HD * KC) / (512 * 8);
        const u16* wsrc = Wb + tid * 8;
        u16* ldst = bsh + tid * 8;
#pragma unroll
        for (int i = 0; i < NST; ++i)
            async_cp16(wsrc + i * 4096, ldst + i * 4096);
    }

    int arc[2];
#pragma unroll
    for (int m = 0; m < 2; ++m) {
        const int r = row0 + m * 16 + c;
        arc[m] = r < N ? r : N - 1;
    }

    f32x4 acc[2][12];
#pragma unroll
    for (int m = 0; m < 2; ++m)
#pragma unroll
        for (int f = 0; f < 12; ++f) acc[m][f] = (f32x4){0.f, 0.f, 0.f, 0.f};

    __syncthreads();   // drains global_load_lds; only barrier before epilogue

    for (int ch = 0; ch < NC; ++ch) {
        const int kk = ch * 32;
        bf16x8 a[2];
#pragma unroll
        for (int m = 0; m < 2; ++m) {
            const u16* p = (ch < NC1) ? (A1 + (size_t)arc[m] * K1 + kk + kg * 8)
                                      : (A2 + (size_t)arc[m] * K2 + (kk - K1) + kg * 8);
            a[m] = *(const bf16x8*)p;
        }
#pragma unroll
        for (int f = 0; f < 12; ++f) {
            const bf16x8 b = *(const bf16x8*)&bsh[ch * 6144 + f * 512 + kg * 128 + c * 8];
            acc[0][f] = __builtin_amdgcn_mfma_f32_16x16x32_bf16(a[0], b, acc[0][f], 0, 0, 0);
            acc[1][f] = __builtin_amdgcn_mfma_f32_16x16x32_bf16(a[1], b, acc[1][f], 0, 0, 0);
        }
    }

    // ---- epilogue: bias + store + BN partial sums ----
    float s1v[12], s2v[12];
#pragma unroll
    for (int f = 0; f < 12; ++f) { s1v[f] = 0.f; s2v[f] = 0.f; }

#pragma unroll
    for (int f = 0; f < 12; ++f) {
        const int col = f * 16 + c;
        const float bv = bias[col];
#pragma unroll
        for (int m = 0; m < 2; ++m)
#pragma unroll
            for (int r = 0; r < 4; ++r) {
                const int orow = row0 + m * 16 + kg * 4 + r;
                if (orow < N) {
                    const float v = acc[m][f][r] + bv;
                    s1v[f] += v;
                    s2v[f] += v * v;
                    Hout[(size_t)orow * HD + col] = f2b(v);
                }
            }
    }
#pragma unroll
    for (int f = 0; f < 12; ++f) {
        s1v[f] += __shfl_xor(s1v[f], 16); s1v[f] += __shfl_xor(s1v[f], 32);
        s2v[f] += __shfl_xor(s2v[f], 16); s2v[f] += __shfl_xor(s2v[f], 32);
    }
    __syncthreads();                       // all waves done with bsh
    float* red = (float*)bsh;              // reuse panel LDS: 2 x 8 x 192 floats
    if (kg == 0) {
#pragma unroll
        for (int f = 0; f < 12; ++f) {
            red[wave * HD + f * 16 + c]            = s1v[f];
            red[8 * HD + wave * HD + f * 16 + c]   = s2v[f];
        }
    }
    __syncthreads();
    if (tid < HD) {
        float a1 = 0.f, a2 = 0.f;
#pragma unroll
        for (int w = 0; w < 8; ++w) {
            a1 += red[w * HD + tid];
            a2 += red[8 * HD + w * HD + tid];
        }
        atomicAdd((unsigned long long*)&statsq[tid],
                  (unsigned long long)(long long)llrintf(a1 * STAT_S));
        atomicAdd((unsigned long long*)&statsq[HD + tid],
                  (unsigned long long)(long long)llrintf(a2 * STAT_S));
    }
}

// ------- h = relu(hpre*scale + shift) -> bf16 + i16; BN params from statsq -----
__global__ __launch_bounds__(256) void norm_relu(const u16* __restrict__ hpre,
    u16* __restrict__ hb, short* __restrict__ hq,
    const long long* __restrict__ statsq,
    const float* __restrict__ gamma, const float* __restrict__ beta, int N)
{
    __shared__ float sc[HD], sh[HD];
    const int t = threadIdx.x;
    if (t < HD) {
        const float inv = 1.0f / (float)N;
        const float sum = (float)statsq[t] * STAT_IS;
        const float sq  = (float)statsq[HD + t] * STAT_IS;
        const float mu  = sum * inv;
        const float var = sq * inv - mu * mu;
        const float s   = gamma[t] * rsqrtf(var + BNEPS);
        sc[t] = s; sh[t] = beta[t] - mu * s;
    }
    __syncthreads();
    const int idx = blockIdx.x * 256 + t;
    const int total = N * (HD / 8);
    if (idx >= total) return;
    const int c8 = idx % (HD / 8);
    uint4 packed = ((const uint4*)hpre)[idx];
    const u16* pu = (const u16*)&packed;
    u16 ob[8]; short oq[8];
#pragma unroll
    for (int j = 0; j < 8; ++j) {
        const int cc = c8 * 8 + j;
        const float v = fmaxf(0.f, fmaf(b2f(pu[j]), sc[cc], sh[cc]));
        ob[j] = f2b(v);
        oq[j] = (short)__float2int_rn(fminf(v, 15.9f) * QS);
    }
    ((uint4*)hb)[idx] = *(uint4*)ob;
    ((uint4*)hq)[idx] = *(uint4*)oq;
}

// ------- fused mean-pool + MLP head, parallel rows + coalesced weights -------
__global__ __launch_bounds__(256) void pool_head_kernel(
    const u16* __restrict__ h, const int* __restrict__ batch, int N,
    const float* __restrict__ w1t, const float* __restrict__ b1,
    const float* __restrict__ w2t, const float* __restrict__ b2,
    const float* __restrict__ ow, const float* __restrict__ ob,
    float* __restrict__ out)
{
    __shared__ float pp[8][HD];
    __shared__ float gv[HD];
    __shared__ float h1[HD];
    __shared__ float h2[HD];
    const int g = blockIdx.x;
    const int t = threadIdx.x;
    const int rp = t >> 5;
    const int o  = t & 31;

    int lo = 0, hi = N;
    while (lo < hi) { int m = (lo + hi) >> 1; if (batch[m] < g) lo = m + 1; else hi = m; }
    const int start = lo;
    hi = N;
    while (lo < hi) { int m = (lo + hi) >> 1; if (batch[m] < g + 1) lo = m + 1; else hi = m; }
    const int end = lo;

    float facc[8];
#pragma unroll
    for (int i = 0; i < 8; ++i) facc[i] = 0.f;
    if (o < 24) {
        for (int r = start + rp; r < end; r += 8) {
            const uint4 pv = *(const uint4*)(h + (size_t)r * HD + o * 8);
            const u16* pu = (const u16*)&pv;
#pragma unroll
            for (int i = 0; i < 8; ++i) facc[i] += b2f(pu[i]);
        }
#pragma unroll
        for (int i = 0; i < 8; ++i) pp[rp][o * 8 + i] = facc[i];
    }
    __syncthreads();
    if (t < HD) {
        float s = 0.f;
#pragma unroll
        for (int r = 0; r < 8; ++r) s += pp[r][t];
        gv[t] = s / fmaxf((float)(end - start), 1.0f);
    }
    __syncthreads();
    if (t < HD) {
        float acc = b1[t];
#pragma unroll 4
        for (int k = 0; k < HD; ++k)
            acc = fmaf(gv[k], w1t[k * HD + t], acc);
        h1[t] = fmaxf(acc, 0.f);
    }
    __syncthreads();
    if (t < HD) {
        float acc = b2[t];
#pragma unroll 4
        for (int k = 0; k < HD; ++k)
            acc = fmaf(h1[k], w2t[k * HD + t], acc);
        h2[t] = acc * ow[t];
    }
    __syncthreads();
    if (t < 64) {
        float s = h2[t] + h2[t + 64] + h2[t + 128];
#pragma unroll
        for (int d = 1; d < 64; d <<= 1) s += __shfl_xor(s, d);
        if (t == 0) out[g] = s + ob[0];
    }
}

extern "C" void kernel_launch(void* const* d_in, const int* in_sizes, int n_in,
                              void* d_out, int out_size, void* d_ws, size_t ws_size,
                              hipStream_t stream)
{
    const float* x       = (const float*)d_in[0];
    const int*   ei      = (const int*)d_in[1];
    const int*   batch   = (const int*)d_in[2];
    const float* w_rel0  = (const float*)d_in[4];
    const float* b_rel0  = (const float*)d_in[5];
    const float* w_root0 = (const float*)d_in[6];
    const float* w_rel   = (const float*)d_in[7];
    const float* b_rel   = (const float*)d_in[8];
    const float* w_root  = (const float*)d_in[9];
    const float* bn_g    = (const float*)d_in[10];
    const float* bn_b    = (const float*)d_in[11];
    const float* hw1     = (const float*)d_in[12];
    const float* hb1     = (const float*)d_in[13];
    const float* hw2     = (const float*)d_in[14];
    const float* hb2     = (const float*)d_in[15];
    const float* ow      = (const float*)d_in[16];
    const float* ob      = (const float*)d_in[17];
    float* out = (float*)d_out;

    const int N = in_sizes[0] / FD0;
    const int E = in_sizes[1] / 2;
    const int* src = ei;
    const int* dst = ei + E;
    const int M = idiv(N, 256);

    char* ws = (char*)d_ws;
    size_t off = 0;
    u16*   xb   = (u16*)(ws + off);   off += (size_t)N * FD0 * 2;
    short* xq   = (short*)(ws + off); off += (size_t)N * FD0 * 2;
    u16*   hb   = (u16*)(ws + off);   off += (size_t)N * HD * 2;
    short* hq   = (short*)(ws + off); off += (size_t)N * HD * 2;
    u16*   aggb = (u16*)(ws + off);   off += (size_t)N * HD * 2;
    u16*   hpre = (u16*)(ws + off);   off += (size_t)N * HD * 2;
    u16*   wp0  = (u16*)(ws + off);   off += (size_t)HD * 2 * FD0 * 2;
    u16*   wp123= (u16*)(ws + off);   off += (size_t)3 * HD * 2 * HD * 2;
    off = (off + 15) & ~(size_t)15;
    float* w1t = (float*)(ws + off); off += (size_t)HD * HD * 4;
    float* w2t = (float*)(ws + off); off += (size_t)HD * HD * 4;
    long long* statsq = (long long*)(ws + off); off += 2 * HD * sizeof(long long);
    int*   rowptr = (int*)(ws + off); off += (size_t)(N + 1) * 4;
    int*   deg    = (int*)(ws + off); off += (size_t)N * 4;
    int*   psum   = (int*)(ws + off); off += (size_t)M * 4;
    int*   eidx   = (int*)(ws + off); off += (size_t)E * 4;

    const dim3 b256(256), b512(512);

    // ---- conversions & CSR build
    convert_x<<<idiv(N * FD0 / 4, 256), b256, 0, stream>>>(x, xb, xq, N * FD0 / 4);
    pack_weights<<<idiv(HD * 2 * FD0, 256), b256, 0, stream>>>(w_rel0, w_root0, wp0, FD0);
    for (int i = 0; i < 3; ++i)
        pack_weights<<<idiv(HD * 2 * HD, 256), b256, 0, stream>>>(
            w_rel + (size_t)i * HD * HD, w_root + (size_t)i * HD * HD,
            wp123 + (size_t)i * HD * 2 * HD, HD);
    transpose_w<<<idiv(HD * HD, 256), b256, 0, stream>>>(hw1, w1t);
    transpose_w<<<idiv(HD * HD, 256), b256, 0, stream>>>(hw2, w2t);
    hipMemsetAsync(deg, 0, (size_t)N * sizeof(int), stream);
    hist_kernel<<<idiv(E, 256), b256, 0, stream>>>(dst, deg, E);
    scan_partial<<<M, b256, 0, stream>>>(deg, psum, N);
    scan_small<<<1, b256, 0, stream>>>(psum, M);
    scan_expand<<<M, b256, 0, stream>>>(deg, psum, rowptr, N, E);
    hipMemsetAsync(deg, 0, (size_t)N * sizeof(int), stream);
    fill_kernel<<<idiv(E, 256), b256, 0, stream>>>(src, dst, rowptr, deg, eidx, E);

    // ---- layer 0 (K=128+128)
    hipMemsetAsync(statsq, 0, 2 * HD * sizeof(long long), stream);
    gather_kernel<FD0><<<idiv(N, 4), b256, 0, stream>>>(xq, rowptr, eidx, aggb, N);
    gemm_mfma<FD0, FD0><<<idiv(N, 256), b512, 0, stream>>>(aggb, xb, wp0, b_rel0,
                                                           hpre, statsq, N);
    norm_relu<<<idiv(N * (HD / 8), 256), b256, 0, stream>>>(hpre, hb, hq, statsq,
                                                            bn_g, bn_b, N);

    // ---- layers 1..3 (K=192+192)
    for (int i = 0; i < 3; ++i) {
        hipMemsetAsync(statsq, 0, 2 * HD * sizeof(long long), stream);
        gather_kernel<HD><<<idiv(N, 4), b256, 0, stream>>>(hq, rowptr, eidx, aggb, N);
        gemm_mfma<HD, HD><<<idiv(N, 256), b512, 0, stream>>>(
            aggb, hb, wp123 + (size_t)i * HD * 2 * HD,
            b_rel + (size_t)i * HD, hpre, statsq, N);
        norm_relu<<<idiv(N * (HD / 8), 256), b256, 0, stream>>>(hpre, hb, hq, statsq,
            bn_g + (size_t)(i + 1) * HD, bn_b + (size_t)(i + 1) * HD, N);
    }

    // ---- fused global mean pool + head
    pool_head_kernel<<<NG, b256, 0, stream>>>(hb, batch, N, w1t, hb1, w2t, hb2,
                                              ow, ob, out);
}